// Round 2
// baseline (1086.120 us; speedup 1.0000x reference)
//
#include <hip/hip_runtime.h>
#include <stdint.h>

typedef __attribute__((ext_vector_type(8))) short short8;
typedef __attribute__((ext_vector_type(4))) float f32x4;

__device__ __forceinline__ unsigned short f2b(float f) {
  union { float f; uint32_t u; } v; v.f = f;
  uint32_t u = v.u;
  u = u + 0x7fffu + ((u >> 16) & 1u);
  return (unsigned short)(u >> 16);
}
__device__ __forceinline__ float b2f(unsigned short s) {
  union { uint32_t u; float f; } v; v.u = ((uint32_t)s) << 16;
  return v.f;
}

// ---------------- fp32 -> bf16 convert (x) ----------------
__global__ __launch_bounds__(256) void cvt_f32_bf16(const float* __restrict__ in,
                                                    unsigned short* __restrict__ out, int n) {
  int i = (blockIdx.x * 256 + threadIdx.x) * 4;
  if (i < n) {
    float4 v = *(const float4*)(in + i);
    ushort4 o;
    o.x = f2b(v.x); o.y = f2b(v.y); o.z = f2b(v.z); o.w = f2b(v.w);
    *(ushort4*)(out + i) = o;
  }
}

// ---------------- W [K][N] f32 -> Wt [N][K] bf16 ----------------
__global__ __launch_bounds__(256) void transposeW(const float* __restrict__ W,
                                                  unsigned short* __restrict__ Wt,
                                                  int K, int N) {
  __shared__ float tile[32][33];
  int x0 = blockIdx.x * 32, y0 = blockIdx.y * 32;
  int tx = threadIdx.x, ty = threadIdx.y;
  #pragma unroll
  for (int j = 0; j < 4; ++j)
    tile[ty + j * 8][tx] = W[(size_t)(y0 + ty + j * 8) * N + x0 + tx];
  __syncthreads();
  #pragma unroll
  for (int j = 0; j < 4; ++j)
    Wt[(size_t)(x0 + ty + j * 8) * K + y0 + tx] = f2b(tile[tx][ty + j * 8]);
}

// ---------------- GEMM: C[M][N] = A[M][K] * Bt[N][K]^T + bias ----------------
// A, Bt bf16 row-major. 128x128 tile, BK=32, 256 thr = 4 waves (2x2), each wave 64x64.
template<bool OUTF32>
__global__ __launch_bounds__(256) void gemm_bt(const unsigned short* __restrict__ A,
                                               const unsigned short* __restrict__ Bt,
                                               const float* __restrict__ bias,
                                               void* __restrict__ outp,
                                               int M, int N, int K) {
  __shared__ unsigned short As[128 * 32];
  __shared__ unsigned short Bs[128 * 32];
  const int t = threadIdx.x;
  const int lane = t & 63;
  const int w = t >> 6;
  const int wm = w >> 1, wn = w & 1;
  const int m0 = blockIdx.x * 128, n0 = blockIdx.y * 128;
  const f32x4 zero = {0.f, 0.f, 0.f, 0.f};
  f32x4 acc[4][4];
  #pragma unroll
  for (int i = 0; i < 4; ++i)
    #pragma unroll
    for (int j = 0; j < 4; ++j) acc[i][j] = zero;

  const int srow = t >> 2;   // 0..63
  const int sc   = t & 3;    // 16B chunk within 32-elem row

  for (int k0 = 0; k0 < K; k0 += 32) {
    short8 av0 = *(const short8*)(A  + (size_t)(m0 + srow)      * K + k0 + sc * 8);
    short8 av1 = *(const short8*)(A  + (size_t)(m0 + 64 + srow) * K + k0 + sc * 8);
    short8 bv0 = *(const short8*)(Bt + (size_t)(n0 + srow)      * K + k0 + sc * 8);
    short8 bv1 = *(const short8*)(Bt + (size_t)(n0 + 64 + srow) * K + k0 + sc * 8);
    __syncthreads();   // previous iter's LDS reads done
    *(short8*)(As + t * 8)        = av0;
    *(short8*)(As + 2048 + t * 8) = av1;
    *(short8*)(Bs + t * 8)        = bv0;
    *(short8*)(Bs + 2048 + t * 8) = bv1;
    __syncthreads();
    short8 af[4], bfr[4];
    #pragma unroll
    for (int f = 0; f < 4; ++f) {
      af[f]  = *(const short8*)(As + (wm * 64 + f * 16 + (lane & 15)) * 32 + (lane >> 4) * 8);
      bfr[f] = *(const short8*)(Bs + (wn * 64 + f * 16 + (lane & 15)) * 32 + (lane >> 4) * 8);
    }
    #pragma unroll
    for (int fm = 0; fm < 4; ++fm)
      #pragma unroll
      for (int fn = 0; fn < 4; ++fn)
        acc[fm][fn] = __builtin_amdgcn_mfma_f32_16x16x32_bf16(af[fm], bfr[fn], acc[fm][fn], 0, 0, 0);
  }

  const int cl = lane & 15, g = lane >> 4;
  #pragma unroll
  for (int fn = 0; fn < 4; ++fn) {
    int col = n0 + wn * 64 + fn * 16 + cl;
    float bv = bias[col];
    #pragma unroll
    for (int fm = 0; fm < 4; ++fm) {
      int rbase = m0 + wm * 64 + fm * 16 + g * 4;
      #pragma unroll
      for (int r = 0; r < 4; ++r) {
        float vout = acc[fm][fn][r] + bv;
        if (OUTF32) ((float*)outp)[(size_t)(rbase + r) * N + col] = vout;
        else ((unsigned short*)outp)[(size_t)(rbase + r) * N + col] = f2b(vout);
      }
    }
  }
}

// ---------------- causal flash attention, vector-ALU ----------------
// qkv bf16 [B*S][3072]; one wave (64 thr) per 64 q-rows of one (b,h).
// Each lane owns one q row: q[64], acc[64] in VGPRs. K/V tiles (64 rows) in LDS as f32.
#define ZSCALE 0.18033688011112043f   // (1/sqrt(64)) * log2(e)
__global__ __launch_bounds__(64) void attn_flash(const unsigned short* __restrict__ qkv,
                                                 unsigned short* __restrict__ ctx) {
  const int bh = blockIdx.x;
  const int b = bh >> 4, h = bh & 15;
  const int qt = blockIdx.y;
  const int qbase = qt * 64;
  const int lane = threadIdx.x;

  __shared__ float Kt[64][68];
  __shared__ float Vt[64][68];

  const unsigned short* qkv_b = qkv + (size_t)b * 2048 * 3072;

  float q[64];
  {
    const unsigned short* qrow = qkv_b + (size_t)(qbase + lane) * 3072 + h * 64;
    #pragma unroll
    for (int c8 = 0; c8 < 8; ++c8) {
      short8 v = *(const short8*)(qrow + c8 * 8);
      #pragma unroll
      for (int j = 0; j < 8; ++j) q[c8 * 8 + j] = b2f((unsigned short)v[j]);
    }
  }

  float acc[64];
  #pragma unroll
  for (int d = 0; d < 64; ++d) acc[d] = 0.f;
  float m = -1e30f, l = 0.f;

  const int nt = qt + 1;
  for (int jt = 0; jt < nt; ++jt) {
    __syncthreads();
    {
      const unsigned short* krow = qkv_b + (size_t)(jt * 64 + lane) * 3072 + 1024 + h * 64;
      const unsigned short* vrow = krow + 1024;
      #pragma unroll
      for (int c8 = 0; c8 < 8; ++c8) {
        short8 kv = *(const short8*)(krow + c8 * 8);
        short8 vv = *(const short8*)(vrow + c8 * 8);
        #pragma unroll
        for (int j = 0; j < 8; ++j) {
          Kt[lane][c8 * 8 + j] = b2f((unsigned short)kv[j]);
          Vt[lane][c8 * 8 + j] = b2f((unsigned short)vv[j]);
        }
      }
    }
    __syncthreads();

    const bool diag = (jt == qt);
    for (int c = 0; c < 8; ++c) {          // chunks of 8 kv
      float z[8];
      #pragma unroll
      for (int jj = 0; jj < 8; ++jj) {
        int j = c * 8 + jj;
        const float4* kr = (const float4*)(&Kt[j][0]);
        float s = 0.f;
        #pragma unroll
        for (int d4 = 0; d4 < 16; ++d4) {
          float4 kk = kr[d4];
          s += q[d4 * 4 + 0] * kk.x + q[d4 * 4 + 1] * kk.y
             + q[d4 * 4 + 2] * kk.z + q[d4 * 4 + 3] * kk.w;
        }
        z[jj] = s * ZSCALE;
        if (diag && (j > lane)) z[jj] = -1e30f;
      }
      float cm = z[0];
      #pragma unroll
      for (int jj = 1; jj < 8; ++jj) cm = fmaxf(cm, z[jj]);
      float mn = fmaxf(m, cm);
      float alpha = exp2f(m - mn);
      m = mn;
      l *= alpha;
      #pragma unroll
      for (int d = 0; d < 64; ++d) acc[d] *= alpha;
      #pragma unroll
      for (int jj = 0; jj < 8; ++jj) {
        float p = exp2f(z[jj] - m);
        l += p;
        const float4* vr = (const float4*)(&Vt[c * 8 + jj][0]);
        #pragma unroll
        for (int d4 = 0; d4 < 16; ++d4) {
          float4 vv = vr[d4];
          acc[d4 * 4 + 0] += p * vv.x;
          acc[d4 * 4 + 1] += p * vv.y;
          acc[d4 * 4 + 2] += p * vv.z;
          acc[d4 * 4 + 3] += p * vv.w;
        }
      }
    }
  }

  float inv = 1.f / l;
  unsigned short* crow = ctx + (size_t)(b * 2048 + qbase + lane) * 1024 + h * 64;
  #pragma unroll
  for (int c4 = 0; c4 < 16; ++c4) {
    ushort4 o;
    o.x = f2b(acc[c4 * 4 + 0] * inv);
    o.y = f2b(acc[c4 * 4 + 1] * inv);
    o.z = f2b(acc[c4 * 4 + 2] * inv);
    o.w = f2b(acc[c4 * 4 + 3] * inv);
    *(ushort4*)(crow + c4 * 4) = o;
  }
}

// ---------------- launch ----------------
extern "C" void kernel_launch(void* const* d_in, const int* in_sizes, int n_in,
                              void* d_out, int out_size, void* d_ws, size_t ws_size,
                              hipStream_t stream) {
  const float* x     = (const float*)d_in[0];   // [2,2048,1024]
  const float* Wqkv  = (const float*)d_in[1];   // [1024,3072]
  const float* bqkv  = (const float*)d_in[2];   // [3072]
  const float* Wproj = (const float*)d_in[3];   // [1024,1024]
  const float* bproj = (const float*)d_in[4];   // [1024]
  float* out = (float*)d_out;

  char* ws = (char*)d_ws;
  unsigned short* xb     = (unsigned short*)(ws);                 //  8 MB  [4096][1024]
  unsigned short* wqkvT  = (unsigned short*)(ws + 8388608);       //  6 MB  [3072][1024]
  unsigned short* wprojT = (unsigned short*)(ws + 14680064);      //  2 MB  [1024][1024]
  unsigned short* qkv    = (unsigned short*)(ws + 16777216);      // 24 MB  [4096][3072]
  unsigned short* ctx    = (unsigned short*)(ws + 41943040);      //  8 MB  [4096][1024]

  cvt_f32_bf16<<<4096, 256, 0, stream>>>(x, xb, 4096 * 1024);

  dim3 tb(32, 8);
  transposeW<<<dim3(3072 / 32, 1024 / 32), tb, 0, stream>>>(Wqkv, wqkvT, 1024, 3072);
  transposeW<<<dim3(1024 / 32, 1024 / 32), tb, 0, stream>>>(Wproj, wprojT, 1024, 1024);

  gemm_bt<false><<<dim3(32, 24), 256, 0, stream>>>(xb, wqkvT, bqkv, qkv, 4096, 3072, 1024);

  attn_flash<<<dim3(32, 32), 64, 0, stream>>>(qkv, ctx);

  gemm_bt<true><<<dim3(32, 8), 256, 0, stream>>>(ctx, wprojT, bproj, out, 4096, 1024, 1024);
}

// Round 3
// 292.904 us; speedup vs baseline: 3.7081x; 3.7081x over previous
//
#include <hip/hip_runtime.h>
#include <stdint.h>

typedef __attribute__((ext_vector_type(8))) short short8;
typedef __attribute__((ext_vector_type(4))) float f32x4;

__device__ __forceinline__ unsigned short f2b(float f) {
  union { float f; uint32_t u; } v; v.f = f;
  uint32_t u = v.u;
  u = u + 0x7fffu + ((u >> 16) & 1u);
  return (unsigned short)(u >> 16);
}
__device__ __forceinline__ float b2f(unsigned short s) {
  union { uint32_t u; float f; } v; v.u = ((uint32_t)s) << 16;
  return v.f;
}

// ---------------- fp32 -> bf16 convert (x) ----------------
__global__ __launch_bounds__(256) void cvt_f32_bf16(const float* __restrict__ in,
                                                    unsigned short* __restrict__ out, int n) {
  int i = (blockIdx.x * 256 + threadIdx.x) * 4;
  if (i < n) {
    float4 v = *(const float4*)(in + i);
    ushort4 o;
    o.x = f2b(v.x); o.y = f2b(v.y); o.z = f2b(v.z); o.w = f2b(v.w);
    *(ushort4*)(out + i) = o;
  }
}

// ---------------- W [K][N] f32 -> Wt [N][K] bf16 ----------------
__global__ __launch_bounds__(256) void transposeW(const float* __restrict__ W,
                                                  unsigned short* __restrict__ Wt,
                                                  int K, int N) {
  __shared__ float tile[32][33];
  int x0 = blockIdx.x * 32, y0 = blockIdx.y * 32;
  int tx = threadIdx.x, ty = threadIdx.y;
  #pragma unroll
  for (int j = 0; j < 4; ++j)
    tile[ty + j * 8][tx] = W[(size_t)(y0 + ty + j * 8) * N + x0 + tx];
  __syncthreads();
  #pragma unroll
  for (int j = 0; j < 4; ++j)
    Wt[(size_t)(x0 + ty + j * 8) * K + y0 + tx] = f2b(tile[tx][ty + j * 8]);
}

// ---------------- GEMM: C[M][N] = A[M][K] * Bt[N][K]^T + bias ----------------
template<bool OUTF32>
__global__ __launch_bounds__(256) void gemm_bt(const unsigned short* __restrict__ A,
                                               const unsigned short* __restrict__ Bt,
                                               const float* __restrict__ bias,
                                               void* __restrict__ outp,
                                               int M, int N, int K) {
  __shared__ unsigned short As[128 * 32];
  __shared__ unsigned short Bs[128 * 32];
  const int t = threadIdx.x;
  const int lane = t & 63;
  const int w = t >> 6;
  const int wm = w >> 1, wn = w & 1;
  const int m0 = blockIdx.x * 128, n0 = blockIdx.y * 128;
  const f32x4 zero = {0.f, 0.f, 0.f, 0.f};
  f32x4 acc[4][4];
  #pragma unroll
  for (int i = 0; i < 4; ++i)
    #pragma unroll
    for (int j = 0; j < 4; ++j) acc[i][j] = zero;

  const int srow = t >> 2;
  const int sc   = t & 3;

  for (int k0 = 0; k0 < K; k0 += 32) {
    short8 av0 = *(const short8*)(A  + (size_t)(m0 + srow)      * K + k0 + sc * 8);
    short8 av1 = *(const short8*)(A  + (size_t)(m0 + 64 + srow) * K + k0 + sc * 8);
    short8 bv0 = *(const short8*)(Bt + (size_t)(n0 + srow)      * K + k0 + sc * 8);
    short8 bv1 = *(const short8*)(Bt + (size_t)(n0 + 64 + srow) * K + k0 + sc * 8);
    __syncthreads();
    *(short8*)(As + t * 8)        = av0;
    *(short8*)(As + 2048 + t * 8) = av1;
    *(short8*)(Bs + t * 8)        = bv0;
    *(short8*)(Bs + 2048 + t * 8) = bv1;
    __syncthreads();
    short8 af[4], bfr[4];
    #pragma unroll
    for (int f = 0; f < 4; ++f) {
      af[f]  = *(const short8*)(As + (wm * 64 + f * 16 + (lane & 15)) * 32 + (lane >> 4) * 8);
      bfr[f] = *(const short8*)(Bs + (wn * 64 + f * 16 + (lane & 15)) * 32 + (lane >> 4) * 8);
    }
    #pragma unroll
    for (int fm = 0; fm < 4; ++fm)
      #pragma unroll
      for (int fn = 0; fn < 4; ++fn)
        acc[fm][fn] = __builtin_amdgcn_mfma_f32_16x16x32_bf16(af[fm], bfr[fn], acc[fm][fn], 0, 0, 0);
  }

  const int cl = lane & 15, g = lane >> 4;
  #pragma unroll
  for (int fn = 0; fn < 4; ++fn) {
    int col = n0 + wn * 64 + fn * 16 + cl;
    float bv = bias[col];
    #pragma unroll
    for (int fm = 0; fm < 4; ++fm) {
      int rbase = m0 + wm * 64 + fm * 16 + g * 4;
      #pragma unroll
      for (int r = 0; r < 4; ++r) {
        float vout = acc[fm][fn][r] + bv;
        if (OUTF32) ((float*)outp)[(size_t)(rbase + r) * N + col] = vout;
        else ((unsigned short*)outp)[(size_t)(rbase + r) * N + col] = f2b(vout);
      }
    }
  }
}

// ---------------- V transpose: qkv V-part -> Vt[bh][d=64][s=2048] ----------------
__global__ __launch_bounds__(256) void transposeV(const unsigned short* __restrict__ qkv,
                                                  unsigned short* __restrict__ Vt) {
  __shared__ unsigned short tile[64][72];   // 144B rows: 16B-aligned
  const int bh = blockIdx.y, b = bh >> 4, h = bh & 15;
  const int s0 = blockIdx.x * 64;
  const int t = threadIdx.x;
  #pragma unroll
  for (int i = 0; i < 2; ++i) {
    int c = t + i * 256;
    int srow = c >> 3, d0 = (c & 7) * 8;
    short8 v = *(const short8*)(qkv + (size_t)(b * 2048 + s0 + srow) * 3072 + 2048 + h * 64 + d0);
    *(short8*)(&tile[srow][d0]) = v;
  }
  __syncthreads();
  #pragma unroll
  for (int i = 0; i < 2; ++i) {
    int c = t + i * 256;
    int d = c >> 3, sb = (c & 7) * 8;
    short8 o;
    #pragma unroll
    for (int j = 0; j < 8; ++j) o[j] = tile[sb + j][d];
    *(short8*)(Vt + (size_t)(bh * 64 + d) * 2048 + s0 + sb) = o;
  }
}

// ---------------- MFMA causal flash attention ----------------
// Block: 256 thr = 4 waves; q-tile 64 rows (16/wave); kv-tile 64.
// Per wave: QK^T via 16x16x32 bf16 MFMA (S-tiles in D-layout), wave-parallel
// online softmax via shfl_xor row-reduce, P through 2KB per-wave LDS to
// reach A-frag layout, PV via MFMA against Vt (B-frag [d][kv]).
#define ZSCALE 0.18033688011112043f   // (1/sqrt(64)) * log2(e)
__global__ __launch_bounds__(256) void attn_mfma(const unsigned short* __restrict__ qkv,
                                                 const unsigned short* __restrict__ Vt,
                                                 unsigned short* __restrict__ ctx) {
  const int qt = blockIdx.x;
  const int bh = blockIdx.y;
  const int b = bh >> 4, h = bh & 15;
  const int qbase = qt * 64;
  const int t = threadIdx.x;
  const int lane = t & 63;
  const int w = t >> 6;
  const int cl = lane & 15;
  const int g  = lane >> 4;

  __shared__ unsigned short Ks[64 * 64];
  __shared__ unsigned short Vs[64 * 64];
  __shared__ unsigned short Ps[4][16 * 64];

  char* KsB = (char*)Ks;
  char* VsB = (char*)Vs;
  char* PsB = (char*)(&Ps[w][0]);

  // Q fragments (held whole kernel)
  short8 aq[2];
  {
    const unsigned short* qp = qkv + (size_t)(b * 2048 + qbase + w * 16 + cl) * 3072 + h * 64 + g * 8;
    aq[0] = *(const short8*)(qp);
    aq[1] = *(const short8*)(qp + 32);
  }

  f32x4 o[4];
  float mrow[4], lrow[4];
  #pragma unroll
  for (int c = 0; c < 4; ++c) o[c] = (f32x4){0.f, 0.f, 0.f, 0.f};
  #pragma unroll
  for (int r = 0; r < 4; ++r) { mrow[r] = -1e30f; lrow[r] = 0.f; }

  const size_t kbase  = (size_t)(b * 2048) * 3072 + 1024 + h * 64;
  const size_t vtbase = (size_t)(bh * 64) * 2048;

  for (int jt = 0; jt <= qt; ++jt) {
    __syncthreads();
    // ---- stage K, Vt tiles (XOR-swizzled) ----
    #pragma unroll
    for (int i = 0; i < 2; ++i) {
      int c = t + i * 256;                 // 0..511
      int row = c >> 3, cb = (c & 7) * 16;
      short8 kv = *(const short8*)(qkv + kbase + (size_t)(jt * 64 + row) * 3072 + (c & 7) * 8);
      short8 vv = *(const short8*)(Vt + vtbase + (size_t)row * 2048 + jt * 64 + (c & 7) * 8);
      *(short8*)(KsB + ((row * 128 + cb) ^ ((row & 7) << 4))) = kv;
      *(short8*)(VsB + ((row * 128 + cb) ^ ((row & 7) << 4))) = vv;
    }
    __syncthreads();

    // ---- QK^T: 4 kv-tiles x 2 k-steps ----
    f32x4 st[4];
    #pragma unroll
    for (int tt = 0; tt < 4; ++tt) st[tt] = (f32x4){0.f, 0.f, 0.f, 0.f};
    #pragma unroll
    for (int kk = 0; kk < 2; ++kk) {
      #pragma unroll
      for (int tt = 0; tt < 4; ++tt) {
        int row = tt * 16 + cl;
        short8 bk = *(const short8*)(KsB + ((row * 128 + kk * 64 + g * 16) ^ ((row & 7) << 4)));
        st[tt] = __builtin_amdgcn_mfma_f32_16x16x32_bf16(aq[kk], bk, st[tt], 0, 0, 0);
      }
    }

    // ---- scale + causal mask (mask-before-scale semantics: p becomes 0) ----
    float z[4][4];
    #pragma unroll
    for (int tt = 0; tt < 4; ++tt)
      #pragma unroll
      for (int r = 0; r < 4; ++r) z[tt][r] = st[tt][r] * ZSCALE;
    if (jt == qt) {
      #pragma unroll
      for (int tt = 0; tt < 4; ++tt) {
        int kvl = tt * 16 + cl;
        #pragma unroll
        for (int r = 0; r < 4; ++r) {
          int ql = w * 16 + g * 4 + r;
          if (kvl > ql) z[tt][r] = -1e30f;
        }
      }
    }

    // ---- online softmax (rows live across 16-lane groups) ----
    float alpha[4];
    #pragma unroll
    for (int r = 0; r < 4; ++r) {
      float v = fmaxf(fmaxf(z[0][r], z[1][r]), fmaxf(z[2][r], z[3][r]));
      v = fmaxf(v, __shfl_xor(v, 1));
      v = fmaxf(v, __shfl_xor(v, 2));
      v = fmaxf(v, __shfl_xor(v, 4));
      v = fmaxf(v, __shfl_xor(v, 8));
      float mn = fmaxf(mrow[r], v);
      alpha[r] = exp2f(mrow[r] - mn);
      mrow[r] = mn;
    }
    float ps[4] = {0.f, 0.f, 0.f, 0.f};
    unsigned short pb[4][4];
    #pragma unroll
    for (int tt = 0; tt < 4; ++tt)
      #pragma unroll
      for (int r = 0; r < 4; ++r) {
        float p = exp2f(z[tt][r] - mrow[r]);
        ps[r] += p;
        pb[tt][r] = f2b(p);
      }
    #pragma unroll
    for (int r = 0; r < 4; ++r) {
      float v = ps[r];
      v += __shfl_xor(v, 1);
      v += __shfl_xor(v, 2);
      v += __shfl_xor(v, 4);
      v += __shfl_xor(v, 8);
      lrow[r] = lrow[r] * alpha[r] + v;
    }
    #pragma unroll
    for (int c = 0; c < 4; ++c)
      #pragma unroll
      for (int r = 0; r < 4; ++r) o[c][r] *= alpha[r];

    // ---- P: D-layout regs -> LDS -> A-frag layout (per-wave private) ----
    #pragma unroll
    for (int tt = 0; tt < 4; ++tt)
      #pragma unroll
      for (int r = 0; r < 4; ++r) {
        int row = g * 4 + r;
        *(unsigned short*)(PsB + ((row * 128 + (tt * 16 + cl) * 2) ^ ((row & 7) << 4))) = pb[tt][r];
      }
    short8 ap[2];
    #pragma unroll
    for (int kk = 0; kk < 2; ++kk)
      ap[kk] = *(const short8*)(PsB + ((cl * 128 + kk * 64 + g * 16) ^ ((cl & 7) << 4)));

    // ---- PV: 4 d-tiles x 2 kv-steps ----
    #pragma unroll
    for (int kk = 0; kk < 2; ++kk)
      #pragma unroll
      for (int c = 0; c < 4; ++c) {
        int row = c * 16 + cl;
        short8 bv = *(const short8*)(VsB + ((row * 128 + kk * 64 + g * 16) ^ ((row & 7) << 4)));
        o[c] = __builtin_amdgcn_mfma_f32_16x16x32_bf16(ap[kk], bv, o[c], 0, 0, 0);
      }
  }

  // ---- epilogue ----
  #pragma unroll
  for (int r = 0; r < 4; ++r) {
    float inv = 1.f / lrow[r];
    int q = qbase + w * 16 + g * 4 + r;
    unsigned short* crow = ctx + (size_t)(b * 2048 + q) * 1024 + h * 64;
    #pragma unroll
    for (int c = 0; c < 4; ++c)
      crow[c * 16 + cl] = f2b(o[c][r] * inv);
  }
}

// ---------------- launch ----------------
extern "C" void kernel_launch(void* const* d_in, const int* in_sizes, int n_in,
                              void* d_out, int out_size, void* d_ws, size_t ws_size,
                              hipStream_t stream) {
  const float* x     = (const float*)d_in[0];   // [2,2048,1024]
  const float* Wqkv  = (const float*)d_in[1];   // [1024,3072]
  const float* bqkv  = (const float*)d_in[2];   // [3072]
  const float* Wproj = (const float*)d_in[3];   // [1024,1024]
  const float* bproj = (const float*)d_in[4];   // [1024]
  float* out = (float*)d_out;

  char* ws = (char*)d_ws;
  unsigned short* xb     = (unsigned short*)(ws);                 //  8 MB [4096][1024]
  unsigned short* wqkvT  = (unsigned short*)(ws + 8388608);       //  6 MB [3072][1024]
  unsigned short* wprojT = (unsigned short*)(ws + 14680064);      //  2 MB [1024][1024]
  unsigned short* qkv    = (unsigned short*)(ws + 16777216);      // 24 MB [4096][3072]
  unsigned short* ctx    = (unsigned short*)(ws + 41943040);      //  8 MB [4096][1024]
  unsigned short* vt     = (unsigned short*)(ws + 50331648);      //  8 MB [32][64][2048]

  cvt_f32_bf16<<<4096, 256, 0, stream>>>(x, xb, 4096 * 1024);

  dim3 tb(32, 8);
  transposeW<<<dim3(3072 / 32, 1024 / 32), tb, 0, stream>>>(Wqkv, wqkvT, 1024, 3072);
  transposeW<<<dim3(1024 / 32, 1024 / 32), tb, 0, stream>>>(Wproj, wprojT, 1024, 1024);

  gemm_bt<false><<<dim3(32, 24), 256, 0, stream>>>(xb, wqkvT, bqkv, qkv, 4096, 3072, 1024);

  transposeV<<<dim3(32, 32), 256, 0, stream>>>(qkv, vt);

  attn_mfma<<<dim3(32, 32), 256, 0, stream>>>(qkv, vt, ctx);

  gemm_bt<true><<<dim3(32, 8), 256, 0, stream>>>(ctx, wprojT, bproj, out, 4096, 1024, 1024);
}

// Round 4
// 215.153 us; speedup vs baseline: 5.0481x; 1.3614x over previous
//
#include <hip/hip_runtime.h>
#include <stdint.h>

typedef __attribute__((ext_vector_type(8))) short short8;
typedef __attribute__((ext_vector_type(4))) float f32x4;

__device__ __forceinline__ unsigned short f2b(float f) {
  union { float f; uint32_t u; } v; v.f = f;
  uint32_t u = v.u;
  u = u + 0x7fffu + ((u >> 16) & 1u);
  return (unsigned short)(u >> 16);
}
__device__ __forceinline__ float b2f(unsigned short s) {
  union { uint32_t u; float f; } v; v.u = ((uint32_t)s) << 16;
  return v.f;
}
__device__ __forceinline__ unsigned int cvtpk(float lo, float hi) {
  unsigned int r;
  asm("v_cvt_pk_bf16_f32 %0, %1, %2" : "=v"(r) : "v"(lo), "v"(hi));
  return r;
}
__device__ __forceinline__ void gload16(const void* g, void* lds) {
  __builtin_amdgcn_global_load_lds((const __attribute__((address_space(1))) void*)g,
                                   (__attribute__((address_space(3))) void*)lds, 16, 0, 0);
}

// ---------------- fp32 -> bf16 convert (x) ----------------
__global__ __launch_bounds__(256) void cvt_f32_bf16(const float* __restrict__ in,
                                                    unsigned short* __restrict__ out, int n) {
  int i = (blockIdx.x * 256 + threadIdx.x) * 4;
  if (i < n) {
    float4 v = *(const float4*)(in + i);
    ushort4 o;
    o.x = f2b(v.x); o.y = f2b(v.y); o.z = f2b(v.z); o.w = f2b(v.w);
    *(ushort4*)(out + i) = o;
  }
}

// ---------------- W [K][N] f32 -> Wt [N][K] bf16 ----------------
__global__ __launch_bounds__(256) void transposeW(const float* __restrict__ W,
                                                  unsigned short* __restrict__ Wt,
                                                  int K, int N) {
  __shared__ float tile[32][33];
  int x0 = blockIdx.x * 32, y0 = blockIdx.y * 32;
  int tx = threadIdx.x, ty = threadIdx.y;
  #pragma unroll
  for (int j = 0; j < 4; ++j)
    tile[ty + j * 8][tx] = W[(size_t)(y0 + ty + j * 8) * N + x0 + tx];
  __syncthreads();
  #pragma unroll
  for (int j = 0; j < 4; ++j)
    Wt[(size_t)(x0 + ty + j * 8) * K + y0 + tx] = f2b(tile[tx][ty + j * 8]);
}

// ---------------- GEMM: C[M][N] = A[M][K] * Bt[N][K]^T + bias ----------------
// 128x128 tile, BK=32, 4 waves. Staging via global_load_lds width=16 (linear LDS).
template<bool OUTF32>
__global__ __launch_bounds__(256) void gemm_bt(const unsigned short* __restrict__ A,
                                               const unsigned short* __restrict__ Bt,
                                               const float* __restrict__ bias,
                                               void* __restrict__ outp,
                                               int M, int N, int K) {
  __shared__ unsigned short As[128 * 32];
  __shared__ unsigned short Bs[128 * 32];
  const int t = threadIdx.x;
  const int lane = t & 63;
  const int w = t >> 6;
  const int wm = w >> 1, wn = w & 1;
  const int m0 = blockIdx.x * 128, n0 = blockIdx.y * 128;
  const f32x4 zero = {0.f, 0.f, 0.f, 0.f};
  f32x4 acc[4][4];
  #pragma unroll
  for (int i = 0; i < 4; ++i)
    #pragma unroll
    for (int j = 0; j < 4; ++j) acc[i][j] = zero;

  const int srow = t >> 2;   // 0..63 (row within 64-row half)
  const int sc   = t & 3;    // 16B chunk within 64B row

  for (int k0 = 0; k0 < K; k0 += 32) {
    __syncthreads();   // previous iter's LDS reads done
    #pragma unroll
    for (int hh = 0; hh < 2; ++hh) {
      // wave-uniform LDS base + lane*16 == byte (hh*4096 + t*16): row=hh*64+srow, chunk=sc
      gload16(A  + (size_t)(m0 + hh * 64 + srow) * K + k0 + sc * 8,
              (char*)As + hh * 4096 + w * 1024);
      gload16(Bt + (size_t)(n0 + hh * 64 + srow) * K + k0 + sc * 8,
              (char*)Bs + hh * 4096 + w * 1024);
    }
    __syncthreads();   // drains vmcnt -> tiles ready
    short8 af[4], bfr[4];
    #pragma unroll
    for (int f = 0; f < 4; ++f) {
      af[f]  = *(const short8*)(As + (wm * 64 + f * 16 + (lane & 15)) * 32 + (lane >> 4) * 8);
      bfr[f] = *(const short8*)(Bs + (wn * 64 + f * 16 + (lane & 15)) * 32 + (lane >> 4) * 8);
    }
    #pragma unroll
    for (int fm = 0; fm < 4; ++fm)
      #pragma unroll
      for (int fn = 0; fn < 4; ++fn)
        acc[fm][fn] = __builtin_amdgcn_mfma_f32_16x16x32_bf16(af[fm], bfr[fn], acc[fm][fn], 0, 0, 0);
  }

  const int cl = lane & 15, g = lane >> 4;
  #pragma unroll
  for (int fn = 0; fn < 4; ++fn) {
    int col = n0 + wn * 64 + fn * 16 + cl;
    float bv = bias[col];
    #pragma unroll
    for (int fm = 0; fm < 4; ++fm) {
      int rbase = m0 + wm * 64 + fm * 16 + g * 4;
      #pragma unroll
      for (int r = 0; r < 4; ++r) {
        float vout = acc[fm][fn][r] + bv;
        if (OUTF32) ((float*)outp)[(size_t)(rbase + r) * N + col] = vout;
        else ((unsigned short*)outp)[(size_t)(rbase + r) * N + col] = f2b(vout);
      }
    }
  }
}

// ---------------- V transpose: qkv V-part -> Vt[bh][d=64][s=2048] ----------------
__global__ __launch_bounds__(256) void transposeV(const unsigned short* __restrict__ qkv,
                                                  unsigned short* __restrict__ Vt) {
  __shared__ unsigned short tile[64][72];
  const int bh = blockIdx.y, b = bh >> 4, h = bh & 15;
  const int s0 = blockIdx.x * 64;
  const int t = threadIdx.x;
  #pragma unroll
  for (int i = 0; i < 2; ++i) {
    int c = t + i * 256;
    int srow = c >> 3, d0 = (c & 7) * 8;
    short8 v = *(const short8*)(qkv + (size_t)(b * 2048 + s0 + srow) * 3072 + 2048 + h * 64 + d0);
    *(short8*)(&tile[srow][d0]) = v;
  }
  __syncthreads();
  #pragma unroll
  for (int i = 0; i < 2; ++i) {
    int c = t + i * 256;
    int d = c >> 3, sb = (c & 7) * 8;
    short8 o;
    #pragma unroll
    for (int j = 0; j < 8; ++j) o[j] = tile[sb + j][d];
    *(short8*)(Vt + (size_t)(bh * 64 + d) * 2048 + s0 + sb) = o;
  }
}

// ---------------- MFMA causal flash attention v2 ----------------
// 4 waves/block; TWO q-tiles (qt=p and qt=31-p) share staged K/V tiles -> perfect balance.
// Swapped QK^T: st = mfma(A=K, B=Q) = S^T; lane owns q-row cl -> lane-local softmax stats.
// Swapped PV: o = mfma(A=V^T, B=P^T) = O^T; rescale lane-local.
// K/V staged via global_load_lds with source-chunk pre-swizzle; reads XOR-swizzled.
#define ZSCALE 0.18033688011112043f   // (1/sqrt(64)) * log2(e)

__device__ __forceinline__ void qkt_phase(const short8 ak[4][2], const short8 bq[2],
                                          char* Pbuf, f32x4 o[4], float& m, float& l,
                                          bool maskIter, int cl, int g, int w) {
  f32x4 st[4];
  #pragma unroll
  for (int tt = 0; tt < 4; ++tt) st[tt] = (f32x4){0.f, 0.f, 0.f, 0.f};
  #pragma unroll
  for (int kk = 0; kk < 2; ++kk)
    #pragma unroll
    for (int tt = 0; tt < 4; ++tt)
      st[tt] = __builtin_amdgcn_mfma_f32_16x16x32_bf16(ak[tt][kk], bq[kk], st[tt], 0, 0, 0);

  // z[tt][r]: kv_loc = tt*16 + 4g + r, q row = cl (lane-local)
  float z[4][4];
  #pragma unroll
  for (int tt = 0; tt < 4; ++tt)
    #pragma unroll
    for (int r = 0; r < 4; ++r) z[tt][r] = st[tt][r] * ZSCALE;
  if (maskIter) {
    int q_loc = w * 16 + cl;
    #pragma unroll
    for (int tt = 0; tt < 4; ++tt)
      #pragma unroll
      for (int r = 0; r < 4; ++r)
        if (tt * 16 + 4 * g + r > q_loc) z[tt][r] = -1e30f;
  }
  float v = z[0][0];
  #pragma unroll
  for (int tt = 0; tt < 4; ++tt)
    #pragma unroll
    for (int r = 0; r < 4; ++r) v = fmaxf(v, z[tt][r]);
  v = fmaxf(v, __shfl_xor(v, 16));
  v = fmaxf(v, __shfl_xor(v, 32));
  float mn = fmaxf(m, v);
  float alpha = exp2f(m - mn);
  m = mn;
  float ps = 0.f;
  unsigned int pb[4][2];
  #pragma unroll
  for (int tt = 0; tt < 4; ++tt) {
    float p0 = exp2f(z[tt][0] - m), p1 = exp2f(z[tt][1] - m);
    float p2 = exp2f(z[tt][2] - m), p3 = exp2f(z[tt][3] - m);
    ps += (p0 + p1) + (p2 + p3);
    pb[tt][0] = cvtpk(p0, p1);
    pb[tt][1] = cvtpk(p2, p3);
  }
  ps += __shfl_xor(ps, 16);
  ps += __shfl_xor(ps, 32);
  l = l * alpha + ps;
  #pragma unroll
  for (int c = 0; c < 4; ++c)
    #pragma unroll
    for (int r = 0; r < 4; ++r) o[c][r] *= alpha;

  // P^T staging (wave-private): row=q=cl, bytes kv*2, swizzle ^((cl&7)<<4)
  #pragma unroll
  for (int tt = 0; tt < 4; ++tt) {
    uint2 val; val.x = pb[tt][0]; val.y = pb[tt][1];
    *(uint2*)(Pbuf + ((cl * 128 + tt * 32 + g * 8) ^ ((cl & 7) << 4))) = val;
  }
}

__device__ __forceinline__ void pv_phase(const short8 av[4][2], const char* Pbuf,
                                         f32x4 o[4], int cl, int g) {
  short8 bp[2];
  #pragma unroll
  for (int kk = 0; kk < 2; ++kk)
    bp[kk] = *(const short8*)(Pbuf + ((cl * 128 + kk * 64 + g * 16) ^ ((cl & 7) << 4)));
  #pragma unroll
  for (int kk = 0; kk < 2; ++kk)
    #pragma unroll
    for (int c = 0; c < 4; ++c)
      o[c] = __builtin_amdgcn_mfma_f32_16x16x32_bf16(av[c][kk], bp[kk], o[c], 0, 0, 0);
}

__global__ __launch_bounds__(256, 2) void attn_mfma2(const unsigned short* __restrict__ qkv,
                                                     const unsigned short* __restrict__ Vt,
                                                     unsigned short* __restrict__ ctx) {
  const int p  = blockIdx.x;            // pair index 0..15
  const int bh = blockIdx.y;
  const int b = bh >> 4, h = bh & 15;
  const int qtA = p, qtB = 31 - p;
  const int t = threadIdx.x;
  const int l = t & 63;
  const int w = t >> 6;
  const int cl = l & 15;
  const int g  = l >> 4;

  __shared__ unsigned short Ks[64 * 64];
  __shared__ unsigned short Vs[64 * 64];
  __shared__ unsigned short Ps[4][2][16 * 64];

  char* KsB = (char*)Ks;
  char* VsB = (char*)Vs;
  char* PbA = (char*)(&Ps[w][0][0]);
  char* PbB = (char*)(&Ps[w][1][0]);

  const size_t kbase  = (size_t)(b * 2048) * 3072 + 1024 + h * 64;
  const size_t vtbase = (size_t)(bh * 64) * 2048;

  // Q fragments, B-layout: col=q=cl, k=d=kk*32+8g+j
  short8 bqA[2], bqB[2];
  {
    const unsigned short* qa = qkv + (size_t)(b * 2048 + qtA * 64 + w * 16 + cl) * 3072 + h * 64 + g * 8;
    bqA[0] = *(const short8*)(qa);
    bqA[1] = *(const short8*)(qa + 32);
    const unsigned short* qb = qkv + (size_t)(b * 2048 + qtB * 64 + w * 16 + cl) * 3072 + h * 64 + g * 8;
    bqB[0] = *(const short8*)(qb);
    bqB[1] = *(const short8*)(qb + 32);
  }

  f32x4 oA[4], oB[4];
  #pragma unroll
  for (int c = 0; c < 4; ++c) { oA[c] = (f32x4){0.f,0.f,0.f,0.f}; oB[c] = (f32x4){0.f,0.f,0.f,0.f}; }
  float mA = -1e30f, lA = 0.f, mB = -1e30f, lB = 0.f;

  for (int jt = 0; jt <= qtB; ++jt) {
    __syncthreads();   // all waves done reading previous tiles
    // stage K,V (64 rows x 64 elems bf16) via gload_lds; source chunk pre-swizzled
    #pragma unroll
    for (int i = 0; i < 2; ++i) {
      int row = i * 32 + w * 8 + (l >> 3);
      int ch  = (l & 7) ^ (l >> 3);        // (l&7) ^ (row&7)
      gload16(qkv + kbase + (size_t)(jt * 64 + row) * 3072 + ch * 8,
              KsB + i * 4096 + w * 1024);
      gload16(Vt + vtbase + (size_t)row * 2048 + jt * 64 + ch * 8,
              VsB + i * 4096 + w * 1024);
    }
    __syncthreads();   // vmcnt drained -> tiles ready

    // A-frag K: row=kv=tt*16+cl, k=d (shared by both phases)
    short8 ak[4][2];
    #pragma unroll
    for (int tt = 0; tt < 4; ++tt)
      #pragma unroll
      for (int kk = 0; kk < 2; ++kk)
        ak[tt][kk] = *(const short8*)(KsB + (((tt * 16 + cl) * 128 + kk * 64 + g * 16) ^ ((cl & 7) << 4)));

    bool actA = (jt <= qtA);   // block-uniform
    if (actA) qkt_phase(ak, bqA, PbA, oA, mA, lA, jt == qtA, cl, g, w);
    qkt_phase(ak, bqB, PbB, oB, mB, lB, jt == qtB, cl, g, w);

    // A-frag V^T: row=d=c*16+cl, k=kv (shared)
    short8 av[4][2];
    #pragma unroll
    for (int c = 0; c < 4; ++c)
      #pragma unroll
      for (int kk = 0; kk < 2; ++kk)
        av[c][kk] = *(const short8*)(VsB + (((c * 16 + cl) * 128 + kk * 64 + g * 16) ^ ((cl & 7) << 4)));

    if (actA) pv_phase(av, PbA, oA, cl, g);
    pv_phase(av, PbB, oB, cl, g);
  }

  // epilogue: lane holds O[q=cl][d=c*16+4g+r]
  {
    float inv = 1.f / lA;
    unsigned short* crow = ctx + (size_t)(b * 2048 + qtA * 64 + w * 16 + cl) * 1024 + h * 64 + g * 4;
    #pragma unroll
    for (int c = 0; c < 4; ++c) {
      uint2 val;
      val.x = cvtpk(oA[c][0] * inv, oA[c][1] * inv);
      val.y = cvtpk(oA[c][2] * inv, oA[c][3] * inv);
      *(uint2*)(crow + c * 16) = val;
    }
  }
  {
    float inv = 1.f / lB;
    unsigned short* crow = ctx + (size_t)(b * 2048 + qtB * 64 + w * 16 + cl) * 1024 + h * 64 + g * 4;
    #pragma unroll
    for (int c = 0; c < 4; ++c) {
      uint2 val;
      val.x = cvtpk(oB[c][0] * inv, oB[c][1] * inv);
      val.y = cvtpk(oB[c][2] * inv, oB[c][3] * inv);
      *(uint2*)(crow + c * 16) = val;
    }
  }
}

// ---------------- launch ----------------
extern "C" void kernel_launch(void* const* d_in, const int* in_sizes, int n_in,
                              void* d_out, int out_size, void* d_ws, size_t ws_size,
                              hipStream_t stream) {
  const float* x     = (const float*)d_in[0];   // [2,2048,1024]
  const float* Wqkv  = (const float*)d_in[1];   // [1024,3072]
  const float* bqkv  = (const float*)d_in[2];   // [3072]
  const float* Wproj = (const float*)d_in[3];   // [1024,1024]
  const float* bproj = (const float*)d_in[4];   // [1024]
  float* out = (float*)d_out;

  char* ws = (char*)d_ws;
  unsigned short* xb     = (unsigned short*)(ws);                 //  8 MB [4096][1024]
  unsigned short* wqkvT  = (unsigned short*)(ws + 8388608);       //  6 MB [3072][1024]
  unsigned short* wprojT = (unsigned short*)(ws + 14680064);      //  2 MB [1024][1024]
  unsigned short* qkv    = (unsigned short*)(ws + 16777216);      // 24 MB [4096][3072]
  unsigned short* ctx    = (unsigned short*)(ws + 41943040);      //  8 MB [4096][1024]
  unsigned short* vt     = (unsigned short*)(ws + 50331648);      //  8 MB [32][64][2048]

  cvt_f32_bf16<<<4096, 256, 0, stream>>>(x, xb, 4096 * 1024);

  dim3 tb(32, 8);
  transposeW<<<dim3(3072 / 32, 1024 / 32), tb, 0, stream>>>(Wqkv, wqkvT, 1024, 3072);
  transposeW<<<dim3(1024 / 32, 1024 / 32), tb, 0, stream>>>(Wproj, wprojT, 1024, 1024);

  gemm_bt<false><<<dim3(32, 24), 256, 0, stream>>>(xb, wqkvT, bqkv, qkv, 4096, 3072, 1024);

  transposeV<<<dim3(32, 32), 256, 0, stream>>>(qkv, vt);

  attn_mfma2<<<dim3(16, 32), 256, 0, stream>>>(qkv, vt, ctx);

  gemm_bt<true><<<dim3(32, 8), 256, 0, stream>>>(ctx, wprojT, bproj, out, 4096, 1024, 1024);
}

// Round 5
// 212.512 us; speedup vs baseline: 5.1109x; 1.0124x over previous
//
#include <hip/hip_runtime.h>
#include <stdint.h>

typedef __attribute__((ext_vector_type(8))) short short8;
typedef __attribute__((ext_vector_type(4))) float f32x4;

#define QSCALE 0.18033688011112043f   // (1/sqrt(64)) * log2(e), folded into W_q/b_q

__device__ __forceinline__ unsigned short f2b(float f) {
  union { float f; uint32_t u; } v; v.f = f;
  uint32_t u = v.u;
  u = u + 0x7fffu + ((u >> 16) & 1u);
  return (unsigned short)(u >> 16);
}
__device__ __forceinline__ unsigned int cvtpk(float lo, float hi) {
  unsigned int r;
  asm("v_cvt_pk_bf16_f32 %0, %1, %2" : "=v"(r) : "v"(lo), "v"(hi));
  return r;
}
__device__ __forceinline__ void gload16(const void* g, void* lds) {
  __builtin_amdgcn_global_load_lds((const __attribute__((address_space(1))) void*)g,
                                   (__attribute__((address_space(3))) void*)lds, 16, 0, 0);
}

// ---------------- fp32 -> bf16 convert (x) ----------------
__global__ __launch_bounds__(256) void cvt_f32_bf16(const float* __restrict__ in,
                                                    unsigned short* __restrict__ out, int n) {
  int i = (blockIdx.x * 256 + threadIdx.x) * 4;
  if (i < n) {
    float4 v = *(const float4*)(in + i);
    ushort4 o;
    o.x = f2b(v.x); o.y = f2b(v.y); o.z = f2b(v.z); o.w = f2b(v.w);
    *(ushort4*)(out + i) = o;
  }
}

// ---------------- W [K][N] f32 -> Wt [N][K] bf16, rows < scaleRows scaled ----------------
__global__ __launch_bounds__(256) void transposeW(const float* __restrict__ W,
                                                  unsigned short* __restrict__ Wt,
                                                  int K, int N, float scale, int scaleRows) {
  __shared__ float tile[32][33];
  int x0 = blockIdx.x * 32, y0 = blockIdx.y * 32;
  int tx = threadIdx.x, ty = threadIdx.y;
  #pragma unroll
  for (int j = 0; j < 4; ++j)
    tile[ty + j * 8][tx] = W[(size_t)(y0 + ty + j * 8) * N + x0 + tx];
  __syncthreads();
  #pragma unroll
  for (int j = 0; j < 4; ++j) {
    int orow = x0 + ty + j * 8;
    float s = (orow < scaleRows) ? scale : 1.0f;
    Wt[(size_t)orow * K + y0 + tx] = f2b(tile[tx][ty + j * 8] * s);
  }
}

// ---------------- GEMM: C[M][N] = A[M][K] * Bt[N][K]^T + bias ----------------
// 128x128 tile, BK=64, 4 waves. gload_lds w=16, both-sides XOR swizzle, XCD-swizzled 1D grid.
template<bool OUTF32>
__global__ __launch_bounds__(256) void gemm_bt(const unsigned short* __restrict__ A,
                                               const unsigned short* __restrict__ Bt,
                                               const float* __restrict__ bias,
                                               void* __restrict__ outp,
                                               int M, int N, int K,
                                               float bscale, int bscaleN, int mtiles) {
  __shared__ unsigned short As[128 * 64];
  __shared__ unsigned short Bs[128 * 64];
  const int t = threadIdx.x;
  const int lane = t & 63;
  const int w = t >> 6;
  const int wm = w >> 1, wn = w & 1;

  // XCD-aware bijective swizzle (gridDim.x % 8 == 0 by construction)
  const int cpx = gridDim.x >> 3;
  const int swz = (blockIdx.x & 7) * cpx + (blockIdx.x >> 3);
  const int m0 = (swz % mtiles) * 128;
  const int n0 = (swz / mtiles) * 128;

  const f32x4 zero = {0.f, 0.f, 0.f, 0.f};
  f32x4 acc[4][4];
  #pragma unroll
  for (int i = 0; i < 4; ++i)
    #pragma unroll
    for (int j = 0; j < 4; ++j) acc[i][j] = zero;

  const int cl = lane & 15, g = lane >> 4;
  const int srow = t >> 3;             // 0..31
  const int sch  = (t & 7) ^ (srow & 7);  // pre-swizzled source chunk

  char* AsB = (char*)As;
  char* BsB = (char*)Bs;

  for (int k0 = 0; k0 < K; k0 += 64) {
    __syncthreads();   // previous iter's LDS reads done
    #pragma unroll
    for (int r = 0; r < 4; ++r) {
      int row = r * 32 + srow;
      gload16(A  + (size_t)(m0 + row) * K + k0 + sch * 8, AsB + r * 4096 + t * 16);
      gload16(Bt + (size_t)(n0 + row) * K + k0 + sch * 8, BsB + r * 4096 + t * 16);
    }
    __syncthreads();   // drains vmcnt -> tiles ready
    #pragma unroll
    for (int kk = 0; kk < 2; ++kk) {
      short8 af[4], bfr[4];
      #pragma unroll
      for (int f = 0; f < 4; ++f) {
        int arow = wm * 64 + f * 16 + cl;
        int brow = wn * 64 + f * 16 + cl;
        af[f]  = *(const short8*)(AsB + ((arow * 128 + kk * 64 + g * 16) ^ ((cl & 7) << 4)));
        bfr[f] = *(const short8*)(BsB + ((brow * 128 + kk * 64 + g * 16) ^ ((cl & 7) << 4)));
      }
      __builtin_amdgcn_s_setprio(1);
      #pragma unroll
      for (int fm = 0; fm < 4; ++fm)
        #pragma unroll
        for (int fn = 0; fn < 4; ++fn)
          acc[fm][fn] = __builtin_amdgcn_mfma_f32_16x16x32_bf16(af[fm], bfr[fn], acc[fm][fn], 0, 0, 0);
      __builtin_amdgcn_s_setprio(0);
    }
  }

  #pragma unroll
  for (int fn = 0; fn < 4; ++fn) {
    int col = n0 + wn * 64 + fn * 16 + cl;
    float bv = bias[col] * ((col < bscaleN) ? bscale : 1.0f);
    #pragma unroll
    for (int fm = 0; fm < 4; ++fm) {
      int rbase = m0 + wm * 64 + fm * 16 + g * 4;
      #pragma unroll
      for (int r = 0; r < 4; ++r) {
        float vout = acc[fm][fn][r] + bv;
        if (OUTF32) ((float*)outp)[(size_t)(rbase + r) * N + col] = vout;
        else ((unsigned short*)outp)[(size_t)(rbase + r) * N + col] = f2b(vout);
      }
    }
  }
}

// ---------------- V transpose: qkv V-part -> Vt[bh][d=64][s=2048] ----------------
__global__ __launch_bounds__(256) void transposeV(const unsigned short* __restrict__ qkv,
                                                  unsigned short* __restrict__ Vt) {
  __shared__ unsigned short tile[64][72];
  const int bh = blockIdx.y, b = bh >> 4, h = bh & 15;
  const int s0 = blockIdx.x * 64;
  const int t = threadIdx.x;
  #pragma unroll
  for (int i = 0; i < 2; ++i) {
    int c = t + i * 256;
    int srow = c >> 3, d0 = (c & 7) * 8;
    short8 v = *(const short8*)(qkv + (size_t)(b * 2048 + s0 + srow) * 3072 + 2048 + h * 64 + d0);
    *(short8*)(&tile[srow][d0]) = v;
  }
  __syncthreads();
  #pragma unroll
  for (int i = 0; i < 2; ++i) {
    int c = t + i * 256;
    int d = c >> 3, sb = (c & 7) * 8;
    short8 o;
    #pragma unroll
    for (int j = 0; j < 8; ++j) o[j] = tile[sb + j][d];
    *(short8*)(Vt + (size_t)(bh * 64 + d) * 2048 + s0 + sb) = o;
  }
}

// ---------------- MFMA causal flash attention v3 ----------------
// As v2 (pairing, swapped operands) plus: pre-scaled Q (no per-elem scale),
// l via ones-row PV MFMA (no ps reduction), defer-max THR=8, setprio on MFMA.
__device__ __forceinline__ void attn_tile(const short8 ak[4][2], const short8 av[4][2],
                                          const short8 a5[2], const short8 bq[2],
                                          char* Pbuf, f32x4 o[4], f32x4& o5,
                                          float& m, bool maskIter, int cl, int g, int w) {
  f32x4 st[4];
  #pragma unroll
  for (int tt = 0; tt < 4; ++tt) st[tt] = (f32x4){0.f, 0.f, 0.f, 0.f};
  __builtin_amdgcn_s_setprio(1);
  #pragma unroll
  for (int kk = 0; kk < 2; ++kk)
    #pragma unroll
    for (int tt = 0; tt < 4; ++tt)
      st[tt] = __builtin_amdgcn_mfma_f32_16x16x32_bf16(ak[tt][kk], bq[kk], st[tt], 0, 0, 0);
  __builtin_amdgcn_s_setprio(0);

  // z already in exp2 domain (scale folded into Q). kv_loc = tt*16+4g+r, q row = cl.
  float z[4][4];
  #pragma unroll
  for (int tt = 0; tt < 4; ++tt)
    #pragma unroll
    for (int r = 0; r < 4; ++r) z[tt][r] = st[tt][r];
  if (maskIter) {
    int q_loc = w * 16 + cl;
    #pragma unroll
    for (int tt = 0; tt < 4; ++tt)
      #pragma unroll
      for (int r = 0; r < 4; ++r)
        if (tt * 16 + 4 * g + r > q_loc) z[tt][r] = -1e30f;
  }
  float cm = z[0][0];
  #pragma unroll
  for (int tt = 0; tt < 4; ++tt)
    #pragma unroll
    for (int r = 0; r < 4; ++r) cm = fmaxf(cm, z[tt][r]);
  cm = fmaxf(cm, __shfl_xor(cm, 16));
  cm = fmaxf(cm, __shfl_xor(cm, 32));

  // defer-max: only rescale when some row grew by > 8 (p stays <= 2^8)
  if (!__all(cm <= m + 8.f)) {
    float mn = fmaxf(m, cm);
    float alpha = exp2f(m - mn);
    m = mn;
    #pragma unroll
    for (int c = 0; c < 4; ++c)
      #pragma unroll
      for (int r = 0; r < 4; ++r) o[c][r] *= alpha;
    o5[0] *= alpha;
  }

  #pragma unroll
  for (int tt = 0; tt < 4; ++tt) {
    float p0 = exp2f(z[tt][0] - m), p1 = exp2f(z[tt][1] - m);
    float p2 = exp2f(z[tt][2] - m), p3 = exp2f(z[tt][3] - m);
    uint2 val;
    val.x = cvtpk(p0, p1);
    val.y = cvtpk(p2, p3);
    *(uint2*)(Pbuf + ((cl * 128 + tt * 32 + g * 8) ^ ((cl & 7) << 4))) = val;
  }
  short8 bp[2];
  #pragma unroll
  for (int kk = 0; kk < 2; ++kk)
    bp[kk] = *(const short8*)(Pbuf + ((cl * 128 + kk * 64 + g * 16) ^ ((cl & 7) << 4)));

  __builtin_amdgcn_s_setprio(1);
  #pragma unroll
  for (int kk = 0; kk < 2; ++kk) {
    #pragma unroll
    for (int c = 0; c < 4; ++c)
      o[c] = __builtin_amdgcn_mfma_f32_16x16x32_bf16(av[c][kk], bp[kk], o[c], 0, 0, 0);
    o5 = __builtin_amdgcn_mfma_f32_16x16x32_bf16(a5[kk], bp[kk], o5, 0, 0, 0);
  }
  __builtin_amdgcn_s_setprio(0);
}

__global__ __launch_bounds__(256, 2) void attn_mfma2(const unsigned short* __restrict__ qkv,
                                                     const unsigned short* __restrict__ Vt,
                                                     unsigned short* __restrict__ ctx) {
  const int p  = blockIdx.x;            // pair index 0..15
  const int bh = blockIdx.y;
  const int b = bh >> 4, h = bh & 15;
  const int qtA = p, qtB = 31 - p;
  const int t = threadIdx.x;
  const int l = t & 63;
  const int w = t >> 6;
  const int cl = l & 15;
  const int g  = l >> 4;

  __shared__ unsigned short Ks[64 * 64];
  __shared__ unsigned short Vs[64 * 64];
  __shared__ unsigned short Ps[4][2][16 * 64];
  __shared__ unsigned short Ones[16 * 64];

  char* KsB = (char*)Ks;
  char* VsB = (char*)Vs;
  char* PbA = (char*)(&Ps[w][0][0]);
  char* PbB = (char*)(&Ps[w][1][0]);
  char* OnB = (char*)Ones;

  // ones-tile: row 0 = 1.0bf16, rows 1..15 = 0 (swizzled like Vs)
  {
    int row = t >> 4;
    int c4  = (t & 15) * 4;
    unsigned short vv = (row == 0) ? (unsigned short)0x3F80 : (unsigned short)0;
    ushort4 ov = {vv, vv, vv, vv};
    *(ushort4*)(OnB + ((row * 128 + c4 * 2) ^ ((row & 7) << 4))) = ov;
  }
  __syncthreads();
  short8 a5[2];
  #pragma unroll
  for (int kk = 0; kk < 2; ++kk)
    a5[kk] = *(const short8*)(OnB + ((cl * 128 + kk * 64 + g * 16) ^ ((cl & 7) << 4)));

  const size_t kbase  = (size_t)(b * 2048) * 3072 + 1024 + h * 64;
  const size_t vtbase = (size_t)(bh * 64) * 2048;

  // Q fragments (pre-scaled by QSCALE via W_q/b_q), B-layout: col=q=cl, k=d
  short8 bqA[2], bqB[2];
  {
    const unsigned short* qa = qkv + (size_t)(b * 2048 + qtA * 64 + w * 16 + cl) * 3072 + h * 64 + g * 8;
    bqA[0] = *(const short8*)(qa);
    bqA[1] = *(const short8*)(qa + 32);
    const unsigned short* qb = qkv + (size_t)(b * 2048 + qtB * 64 + w * 16 + cl) * 3072 + h * 64 + g * 8;
    bqB[0] = *(const short8*)(qb);
    bqB[1] = *(const short8*)(qb + 32);
  }

  f32x4 oA[4], oB[4], o5A, o5B;
  #pragma unroll
  for (int c = 0; c < 4; ++c) { oA[c] = (f32x4){0.f,0.f,0.f,0.f}; oB[c] = (f32x4){0.f,0.f,0.f,0.f}; }
  o5A = (f32x4){0.f,0.f,0.f,0.f};
  o5B = (f32x4){0.f,0.f,0.f,0.f};
  float mA = -1e30f, mB = -1e30f;

  for (int jt = 0; jt <= qtB; ++jt) {
    __syncthreads();   // all waves done reading previous tiles
    #pragma unroll
    for (int i = 0; i < 2; ++i) {
      int row = i * 32 + w * 8 + (l >> 3);
      int ch  = (l & 7) ^ (l >> 3);        // (l&7) ^ (row&7)
      gload16(qkv + kbase + (size_t)(jt * 64 + row) * 3072 + ch * 8,
              KsB + i * 4096 + w * 1024);
      gload16(Vt + vtbase + (size_t)row * 2048 + jt * 64 + ch * 8,
              VsB + i * 4096 + w * 1024);
    }
    __syncthreads();   // vmcnt drained -> tiles ready

    // A-frag K: row=kv=tt*16+cl, k=d
    short8 ak[4][2];
    #pragma unroll
    for (int tt = 0; tt < 4; ++tt)
      #pragma unroll
      for (int kk = 0; kk < 2; ++kk)
        ak[tt][kk] = *(const short8*)(KsB + (((tt * 16 + cl) * 128 + kk * 64 + g * 16) ^ ((cl & 7) << 4)));
    // A-frag V^T: row=d=c*16+cl, k=kv
    short8 av[4][2];
    #pragma unroll
    for (int c = 0; c < 4; ++c)
      #pragma unroll
      for (int kk = 0; kk < 2; ++kk)
        av[c][kk] = *(const short8*)(VsB + (((c * 16 + cl) * 128 + kk * 64 + g * 16) ^ ((cl & 7) << 4)));

    if (jt <= qtA) attn_tile(ak, av, a5, bqA, PbA, oA, o5A, mA, jt == qtA, cl, g, w);
    attn_tile(ak, av, a5, bqB, PbB, oB, o5B, mB, jt == qtB, cl, g, w);
  }

  // epilogue: lane holds O^T[d=c*16+4g+r][q=cl]; l lives in o5[0] on g==0 lanes
  {
    float lsum = __shfl(o5A[0], cl);
    float inv = 1.f / lsum;
    unsigned short* crow = ctx + (size_t)(b * 2048 + qtA * 64 + w * 16 + cl) * 1024 + h * 64 + g * 4;
    #pragma unroll
    for (int c = 0; c < 4; ++c) {
      uint2 val;
      val.x = cvtpk(oA[c][0] * inv, oA[c][1] * inv);
      val.y = cvtpk(oA[c][2] * inv, oA[c][3] * inv);
      *(uint2*)(crow + c * 16) = val;
    }
  }
  {
    float lsum = __shfl(o5B[0], cl);
    float inv = 1.f / lsum;
    unsigned short* crow = ctx + (size_t)(b * 2048 + qtB * 64 + w * 16 + cl) * 1024 + h * 64 + g * 4;
    #pragma unroll
    for (int c = 0; c < 4; ++c) {
      uint2 val;
      val.x = cvtpk(oB[c][0] * inv, oB[c][1] * inv);
      val.y = cvtpk(oB[c][2] * inv, oB[c][3] * inv);
      *(uint2*)(crow + c * 16) = val;
    }
  }
}

// ---------------- launch ----------------
extern "C" void kernel_launch(void* const* d_in, const int* in_sizes, int n_in,
                              void* d_out, int out_size, void* d_ws, size_t ws_size,
                              hipStream_t stream) {
  const float* x     = (const float*)d_in[0];   // [2,2048,1024]
  const float* Wqkv  = (const float*)d_in[1];   // [1024,3072]
  const float* bqkv  = (const float*)d_in[2];   // [3072]
  const float* Wproj = (const float*)d_in[3];   // [1024,1024]
  const float* bproj = (const float*)d_in[4];   // [1024]
  float* out = (float*)d_out;

  char* ws = (char*)d_ws;
  unsigned short* xb     = (unsigned short*)(ws);                 //  8 MB [4096][1024]
  unsigned short* wqkvT  = (unsigned short*)(ws + 8388608);       //  6 MB [3072][1024]
  unsigned short* wprojT = (unsigned short*)(ws + 14680064);      //  2 MB [1024][1024]
  unsigned short* qkv    = (unsigned short*)(ws + 16777216);      // 24 MB [4096][3072]
  unsigned short* ctx    = (unsigned short*)(ws + 41943040);      //  8 MB [4096][1024]
  unsigned short* vt     = (unsigned short*)(ws + 50331648);      //  8 MB [32][64][2048]

  cvt_f32_bf16<<<4096, 256, 0, stream>>>(x, xb, 4096 * 1024);

  dim3 tb(32, 8);
  transposeW<<<dim3(3072 / 32, 1024 / 32), tb, 0, stream>>>(Wqkv, wqkvT, 1024, 3072, QSCALE, 1024);
  transposeW<<<dim3(1024 / 32, 1024 / 32), tb, 0, stream>>>(Wproj, wprojT, 1024, 1024, 1.0f, 0);

  // qkv GEMM: grid 32x24 = 768 (1D, %8==0), Q-bias scaled
  gemm_bt<false><<<768, 256, 0, stream>>>(xb, wqkvT, bqkv, qkv, 4096, 3072, 1024,
                                          QSCALE, 1024, 32);

  transposeV<<<dim3(32, 32), 256, 0, stream>>>(qkv, vt);

  attn_mfma2<<<dim3(16, 32), 256, 0, stream>>>(qkv, vt, ctx);

  // proj GEMM: grid 32x8 = 256
  gemm_bt<true><<<256, 256, 0, stream>>>(ctx, wprojT, bproj, out, 4096, 1024, 1024,
                                         1.0f, 0, 32);
}

// Round 6
// 197.738 us; speedup vs baseline: 5.4927x; 1.0747x over previous
//
#include <hip/hip_runtime.h>
#include <stdint.h>

typedef __attribute__((ext_vector_type(8))) short short8;
typedef __attribute__((ext_vector_type(4))) float f32x4;

#define QSCALE 0.18033688011112043f   // (1/sqrt(64)) * log2(e), folded into W_q/b_q

__device__ __forceinline__ unsigned short f2b(float f) {
  union { float f; uint32_t u; } v; v.f = f;
  uint32_t u = v.u;
  u = u + 0x7fffu + ((u >> 16) & 1u);
  return (unsigned short)(u >> 16);
}
__device__ __forceinline__ unsigned int cvtpk(float lo, float hi) {
  unsigned int r;
  asm("v_cvt_pk_bf16_f32 %0, %1, %2" : "=v"(r) : "v"(lo), "v"(hi));
  return r;
}
__device__ __forceinline__ void gload16(const void* g, void* lds) {
  __builtin_amdgcn_global_load_lds((const __attribute__((address_space(1))) void*)g,
                                   (__attribute__((address_space(3))) void*)lds, 16, 0, 0);
}

// ---------------- fp32 -> bf16 convert (x) ----------------
__global__ __launch_bounds__(256) void cvt_f32_bf16(const float* __restrict__ in,
                                                    unsigned short* __restrict__ out, int n) {
  int i = (blockIdx.x * 256 + threadIdx.x) * 4;
  if (i < n) {
    float4 v = *(const float4*)(in + i);
    ushort4 o;
    o.x = f2b(v.x); o.y = f2b(v.y); o.z = f2b(v.z); o.w = f2b(v.w);
    *(ushort4*)(out + i) = o;
  }
}

// ---------------- W [K][N] f32 -> Wt [N][K] bf16, rows < scaleRows scaled ----------------
__global__ __launch_bounds__(256) void transposeW(const float* __restrict__ W,
                                                  unsigned short* __restrict__ Wt,
                                                  int K, int N, float scale, int scaleRows) {
  __shared__ float tile[32][33];
  int x0 = blockIdx.x * 32, y0 = blockIdx.y * 32;
  int tx = threadIdx.x, ty = threadIdx.y;
  #pragma unroll
  for (int j = 0; j < 4; ++j)
    tile[ty + j * 8][tx] = W[(size_t)(y0 + ty + j * 8) * N + x0 + tx];
  __syncthreads();
  #pragma unroll
  for (int j = 0; j < 4; ++j) {
    int orow = x0 + ty + j * 8;
    float s = (orow < scaleRows) ? scale : 1.0f;
    Wt[(size_t)orow * K + y0 + tx] = f2b(tile[tx][ty + j * 8] * s);
  }
}

// ---------------- GEMM: C[M][N] = A[M][K] * Bt[N][K]^T + bias ----------------
// 128x128 tile, BK=64, 4 waves. gload_lds w=16, both-sides XOR swizzle,
// XCD-swizzled 1D grid, double-buffered LDS (prefetch t+1, ONE barrier/iter).
template<bool OUTF32>
__global__ __launch_bounds__(256) void gemm_bt(const unsigned short* __restrict__ A,
                                               const unsigned short* __restrict__ Bt,
                                               const float* __restrict__ bias,
                                               void* __restrict__ outp,
                                               int M, int N, int K,
                                               float bscale, int bscaleN, int mtiles) {
  __shared__ unsigned short As[2][128 * 64];
  __shared__ unsigned short Bs[2][128 * 64];
  const int t = threadIdx.x;
  const int lane = t & 63;
  const int w = t >> 6;
  const int wm = w >> 1, wn = w & 1;

  const int cpx = gridDim.x >> 3;
  const int swz = (blockIdx.x & 7) * cpx + (blockIdx.x >> 3);
  const int m0 = (swz % mtiles) * 128;
  const int n0 = (swz / mtiles) * 128;

  const f32x4 zero = {0.f, 0.f, 0.f, 0.f};
  f32x4 acc[4][4];
  #pragma unroll
  for (int i = 0; i < 4; ++i)
    #pragma unroll
    for (int j = 0; j < 4; ++j) acc[i][j] = zero;

  const int cl = lane & 15, g = lane >> 4;
  const int srow = t >> 3;               // 0..31
  const int sch  = (t & 7) ^ (srow & 7); // pre-swizzled source chunk

  auto stage = [&](int k0, int buf) {
    #pragma unroll
    for (int r = 0; r < 4; ++r) {
      int row = r * 32 + srow;
      gload16(A  + (size_t)(m0 + row) * K + k0 + sch * 8, (char*)As[buf] + r * 4096 + t * 16);
      gload16(Bt + (size_t)(n0 + row) * K + k0 + sch * 8, (char*)Bs[buf] + r * 4096 + t * 16);
    }
  };

  stage(0, 0);
  __syncthreads();                       // buf0 ready (vmcnt drained)

  const int nk = K >> 6;
  for (int ki = 0; ki < nk; ++ki) {
    const int cur = ki & 1;
    if (ki + 1 < nk) stage((ki + 1) << 6, cur ^ 1);   // prefetch, don't wait
    char* AsB = (char*)As[cur];
    char* BsB = (char*)Bs[cur];
    #pragma unroll
    for (int kk = 0; kk < 2; ++kk) {
      short8 af[4], bfr[4];
      #pragma unroll
      for (int f = 0; f < 4; ++f) {
        int arow = wm * 64 + f * 16 + cl;
        int brow = wn * 64 + f * 16 + cl;
        af[f]  = *(const short8*)(AsB + ((arow * 128 + kk * 64 + g * 16) ^ ((cl & 7) << 4)));
        bfr[f] = *(const short8*)(BsB + ((brow * 128 + kk * 64 + g * 16) ^ ((cl & 7) << 4)));
      }
      #pragma unroll
      for (int fm = 0; fm < 4; ++fm)
        #pragma unroll
        for (int fn = 0; fn < 4; ++fn)
          acc[fm][fn] = __builtin_amdgcn_mfma_f32_16x16x32_bf16(af[fm], bfr[fn], acc[fm][fn], 0, 0, 0);
    }
    __syncthreads();                     // drains prefetch (latency hidden) + read/write sync
  }

  #pragma unroll
  for (int fn = 0; fn < 4; ++fn) {
    int col = n0 + wn * 64 + fn * 16 + cl;
    float bv = bias[col] * ((col < bscaleN) ? bscale : 1.0f);
    #pragma unroll
    for (int fm = 0; fm < 4; ++fm) {
      int rbase = m0 + wm * 64 + fm * 16 + g * 4;
      #pragma unroll
      for (int r = 0; r < 4; ++r) {
        float vout = acc[fm][fn][r] + bv;
        if (OUTF32) ((float*)outp)[(size_t)(rbase + r) * N + col] = vout;
        else ((unsigned short*)outp)[(size_t)(rbase + r) * N + col] = f2b(vout);
      }
    }
  }
}

// ---------------- V transpose: qkv V-part -> Vt[bh][d=64][s=2048] ----------------
__global__ __launch_bounds__(256) void transposeV(const unsigned short* __restrict__ qkv,
                                                  unsigned short* __restrict__ Vt) {
  __shared__ unsigned short tile[64][72];
  const int bh = blockIdx.y, b = bh >> 4, h = bh & 15;
  const int s0 = blockIdx.x * 64;
  const int t = threadIdx.x;
  #pragma unroll
  for (int i = 0; i < 2; ++i) {
    int c = t + i * 256;
    int srow = c >> 3, d0 = (c & 7) * 8;
    short8 v = *(const short8*)(qkv + (size_t)(b * 2048 + s0 + srow) * 3072 + 2048 + h * 64 + d0);
    *(short8*)(&tile[srow][d0]) = v;
  }
  __syncthreads();
  #pragma unroll
  for (int i = 0; i < 2; ++i) {
    int c = t + i * 256;
    int d = c >> 3, sb = (c & 7) * 8;
    short8 o;
    #pragma unroll
    for (int j = 0; j < 8; ++j) o[j] = tile[sb + j][d];
    *(short8*)(Vt + (size_t)(bh * 64 + d) * 2048 + s0 + sb) = o;
  }
}

// ---------------- MFMA causal flash attention v4 ----------------
// v3 (pairing, swapped operands, pre-scaled Q, ones-row l, defer-max) plus
// double-buffered K/V: prefetch jt+1 before compute, ONE barrier per iter.
__device__ __forceinline__ void attn_tile(const short8 ak[4][2], const short8 av[4][2],
                                          const short8 a5[2], const short8 bq[2],
                                          char* Pbuf, f32x4 o[4], f32x4& o5,
                                          float& m, bool maskIter, int cl, int g, int w) {
  f32x4 st[4];
  #pragma unroll
  for (int tt = 0; tt < 4; ++tt) st[tt] = (f32x4){0.f, 0.f, 0.f, 0.f};
  __builtin_amdgcn_s_setprio(1);
  #pragma unroll
  for (int kk = 0; kk < 2; ++kk)
    #pragma unroll
    for (int tt = 0; tt < 4; ++tt)
      st[tt] = __builtin_amdgcn_mfma_f32_16x16x32_bf16(ak[tt][kk], bq[kk], st[tt], 0, 0, 0);
  __builtin_amdgcn_s_setprio(0);

  float z[4][4];
  #pragma unroll
  for (int tt = 0; tt < 4; ++tt)
    #pragma unroll
    for (int r = 0; r < 4; ++r) z[tt][r] = st[tt][r];
  if (maskIter) {
    int q_loc = w * 16 + cl;
    #pragma unroll
    for (int tt = 0; tt < 4; ++tt)
      #pragma unroll
      for (int r = 0; r < 4; ++r)
        if (tt * 16 + 4 * g + r > q_loc) z[tt][r] = -1e30f;
  }
  float cm = z[0][0];
  #pragma unroll
  for (int tt = 0; tt < 4; ++tt)
    #pragma unroll
    for (int r = 0; r < 4; ++r) cm = fmaxf(cm, z[tt][r]);
  cm = fmaxf(cm, __shfl_xor(cm, 16));
  cm = fmaxf(cm, __shfl_xor(cm, 32));

  if (!__all(cm <= m + 8.f)) {           // defer-max THR=8
    float mn = fmaxf(m, cm);
    float alpha = exp2f(m - mn);
    m = mn;
    #pragma unroll
    for (int c = 0; c < 4; ++c)
      #pragma unroll
      for (int r = 0; r < 4; ++r) o[c][r] *= alpha;
    o5[0] *= alpha;
  }

  #pragma unroll
  for (int tt = 0; tt < 4; ++tt) {
    float p0 = exp2f(z[tt][0] - m), p1 = exp2f(z[tt][1] - m);
    float p2 = exp2f(z[tt][2] - m), p3 = exp2f(z[tt][3] - m);
    uint2 val;
    val.x = cvtpk(p0, p1);
    val.y = cvtpk(p2, p3);
    *(uint2*)(Pbuf + ((cl * 128 + tt * 32 + g * 8) ^ ((cl & 7) << 4))) = val;
  }
  short8 bp[2];
  #pragma unroll
  for (int kk = 0; kk < 2; ++kk)
    bp[kk] = *(const short8*)(Pbuf + ((cl * 128 + kk * 64 + g * 16) ^ ((cl & 7) << 4)));

  __builtin_amdgcn_s_setprio(1);
  #pragma unroll
  for (int kk = 0; kk < 2; ++kk) {
    #pragma unroll
    for (int c = 0; c < 4; ++c)
      o[c] = __builtin_amdgcn_mfma_f32_16x16x32_bf16(av[c][kk], bp[kk], o[c], 0, 0, 0);
    o5 = __builtin_amdgcn_mfma_f32_16x16x32_bf16(a5[kk], bp[kk], o5, 0, 0, 0);
  }
  __builtin_amdgcn_s_setprio(0);
}

__global__ __launch_bounds__(256, 2) void attn_mfma2(const unsigned short* __restrict__ qkv,
                                                     const unsigned short* __restrict__ Vt,
                                                     unsigned short* __restrict__ ctx) {
  const int p  = blockIdx.x;            // pair index 0..15
  const int bh = blockIdx.y;
  const int b = bh >> 4, h = bh & 15;
  const int qtA = p, qtB = 31 - p;
  const int t = threadIdx.x;
  const int l = t & 63;
  const int w = t >> 6;
  const int cl = l & 15;
  const int g  = l >> 4;

  __shared__ unsigned short Ks[2][64 * 64];
  __shared__ unsigned short Vs[2][64 * 64];
  __shared__ unsigned short Ps[4][2][16 * 64];
  __shared__ unsigned short Ones[16 * 64];

  char* PbA = (char*)(&Ps[w][0][0]);
  char* PbB = (char*)(&Ps[w][1][0]);
  char* OnB = (char*)Ones;

  const size_t kbase  = (size_t)(b * 2048) * 3072 + 1024 + h * 64;
  const size_t vtbase = (size_t)(bh * 64) * 2048;

  auto stage = [&](int jt, int buf) {
    #pragma unroll
    for (int i = 0; i < 2; ++i) {
      int row = i * 32 + w * 8 + (l >> 3);
      int ch  = (l & 7) ^ (l >> 3);        // (l&7) ^ (row&7)
      gload16(qkv + kbase + (size_t)(jt * 64 + row) * 3072 + ch * 8,
              (char*)Ks[buf] + i * 4096 + w * 1024);
      gload16(Vt + vtbase + (size_t)row * 2048 + jt * 64 + ch * 8,
              (char*)Vs[buf] + i * 4096 + w * 1024);
    }
  };

  // ones-tile: row 0 = 1.0bf16, rows 1..15 = 0 (swizzled like Vs)
  {
    int row = t >> 4;
    int c4  = (t & 15) * 4;
    unsigned short vv = (row == 0) ? (unsigned short)0x3F80 : (unsigned short)0;
    ushort4 ov = {vv, vv, vv, vv};
    *(ushort4*)(OnB + ((row * 128 + c4 * 2) ^ ((row & 7) << 4))) = ov;
  }

  stage(0, 0);                // prologue prefetch
  __syncthreads();            // buf0 + Ones ready

  short8 a5[2];
  #pragma unroll
  for (int kk = 0; kk < 2; ++kk)
    a5[kk] = *(const short8*)(OnB + ((cl * 128 + kk * 64 + g * 16) ^ ((cl & 7) << 4)));

  // Q fragments (pre-scaled by QSCALE via W_q/b_q), B-layout: col=q=cl, k=d
  short8 bqA[2], bqB[2];
  {
    const unsigned short* qa = qkv + (size_t)(b * 2048 + qtA * 64 + w * 16 + cl) * 3072 + h * 64 + g * 8;
    bqA[0] = *(const short8*)(qa);
    bqA[1] = *(const short8*)(qa + 32);
    const unsigned short* qb = qkv + (size_t)(b * 2048 + qtB * 64 + w * 16 + cl) * 3072 + h * 64 + g * 8;
    bqB[0] = *(const short8*)(qb);
    bqB[1] = *(const short8*)(qb + 32);
  }

  f32x4 oA[4], oB[4], o5A, o5B;
  #pragma unroll
  for (int c = 0; c < 4; ++c) { oA[c] = (f32x4){0.f,0.f,0.f,0.f}; oB[c] = (f32x4){0.f,0.f,0.f,0.f}; }
  o5A = (f32x4){0.f,0.f,0.f,0.f};
  o5B = (f32x4){0.f,0.f,0.f,0.f};
  float mA = -1e30f, mB = -1e30f;

  for (int jt = 0; jt <= qtB; ++jt) {
    const int cur = jt & 1;
    if (jt < qtB) stage(jt + 1, cur ^ 1);   // prefetch next tile, don't wait
    char* KsB = (char*)Ks[cur];
    char* VsB = (char*)Vs[cur];

    // A-frag K: row=kv=tt*16+cl, k=d
    short8 ak[4][2];
    #pragma unroll
    for (int tt = 0; tt < 4; ++tt)
      #pragma unroll
      for (int kk = 0; kk < 2; ++kk)
        ak[tt][kk] = *(const short8*)(KsB + (((tt * 16 + cl) * 128 + kk * 64 + g * 16) ^ ((cl & 7) << 4)));
    // A-frag V^T: row=d=c*16+cl, k=kv
    short8 av[4][2];
    #pragma unroll
    for (int c = 0; c < 4; ++c)
      #pragma unroll
      for (int kk = 0; kk < 2; ++kk)
        av[c][kk] = *(const short8*)(VsB + (((c * 16 + cl) * 128 + kk * 64 + g * 16) ^ ((cl & 7) << 4)));

    if (jt <= qtA) attn_tile(ak, av, a5, bqA, PbA, oA, o5A, mA, jt == qtA, cl, g, w);
    attn_tile(ak, av, a5, bqB, PbB, oB, o5B, mB, jt == qtB, cl, g, w);

    __syncthreads();   // drains prefetch (latency hidden under compute) + read/write sync
  }

  // epilogue: lane holds O^T[d=c*16+4g+r][q=cl]; l lives in o5[0] on g==0 lanes
  {
    float lsum = __shfl(o5A[0], cl);
    float inv = 1.f / lsum;
    unsigned short* crow = ctx + (size_t)(b * 2048 + qtA * 64 + w * 16 + cl) * 1024 + h * 64 + g * 4;
    #pragma unroll
    for (int c = 0; c < 4; ++c) {
      uint2 val;
      val.x = cvtpk(oA[c][0] * inv, oA[c][1] * inv);
      val.y = cvtpk(oA[c][2] * inv, oA[c][3] * inv);
      *(uint2*)(crow + c * 16) = val;
    }
  }
  {
    float lsum = __shfl(o5B[0], cl);
    float inv = 1.f / lsum;
    unsigned short* crow = ctx + (size_t)(b * 2048 + qtB * 64 + w * 16 + cl) * 1024 + h * 64 + g * 4;
    #pragma unroll
    for (int c = 0; c < 4; ++c) {
      uint2 val;
      val.x = cvtpk(oB[c][0] * inv, oB[c][1] * inv);
      val.y = cvtpk(oB[c][2] * inv, oB[c][3] * inv);
      *(uint2*)(crow + c * 16) = val;
    }
  }
}

// ---------------- launch ----------------
extern "C" void kernel_launch(void* const* d_in, const int* in_sizes, int n_in,
                              void* d_out, int out_size, void* d_ws, size_t ws_size,
                              hipStream_t stream) {
  const float* x     = (const float*)d_in[0];   // [2,2048,1024]
  const float* Wqkv  = (const float*)d_in[1];   // [1024,3072]
  const float* bqkv  = (const float*)d_in[2];   // [3072]
  const float* Wproj = (const float*)d_in[3];   // [1024,1024]
  const float* bproj = (const float*)d_in[4];   // [1024]
  float* out = (float*)d_out;

  char* ws = (char*)d_ws;
  unsigned short* xb     = (unsigned short*)(ws);                 //  8 MB [4096][1024]
  unsigned short* wqkvT  = (unsigned short*)(ws + 8388608);       //  6 MB [3072][1024]
  unsigned short* wprojT = (unsigned short*)(ws + 14680064);      //  2 MB [1024][1024]
  unsigned short* qkv    = (unsigned short*)(ws + 16777216);      // 24 MB [4096][3072]
  unsigned short* ctx    = (unsigned short*)(ws + 41943040);      //  8 MB [4096][1024]
  unsigned short* vt     = (unsigned short*)(ws + 50331648);      //  8 MB [32][64][2048]

  cvt_f32_bf16<<<4096, 256, 0, stream>>>(x, xb, 4096 * 1024);

  dim3 tb(32, 8);
  transposeW<<<dim3(3072 / 32, 1024 / 32), tb, 0, stream>>>(Wqkv, wqkvT, 1024, 3072, QSCALE, 1024);
  transposeW<<<dim3(1024 / 32, 1024 / 32), tb, 0, stream>>>(Wproj, wprojT, 1024, 1024, 1.0f, 0);

  // qkv GEMM: grid 32x24 = 768 (1D, %8==0), Q-bias scaled
  gemm_bt<false><<<768, 256, 0, stream>>>(xb, wqkvT, bqkv, qkv, 4096, 3072, 1024,
                                          QSCALE, 1024, 32);

  transposeV<<<dim3(32, 32), 256, 0, stream>>>(qkv, vt);

  attn_mfma2<<<dim3(16, 32), 256, 0, stream>>>(qkv, vt, ctx);

  // proj GEMM: grid 32x8 = 256
  gemm_bt<true><<<256, 256, 0, stream>>>(ctx, wprojT, bproj, out, 4096, 1024, 1024,
                                         1.0f, 0, 32);
}

// Round 7
// 191.768 us; speedup vs baseline: 5.6637x; 1.0311x over previous
//
#include <hip/hip_runtime.h>
#include <stdint.h>

typedef __attribute__((ext_vector_type(8))) short short8;
typedef __attribute__((ext_vector_type(4))) float f32x4;

#define QSCALE 0.18033688011112043f   // (1/sqrt(64)) * log2(e), folded into W_q/b_q

__device__ __forceinline__ unsigned short f2b(float f) {
  union { float f; uint32_t u; } v; v.f = f;
  uint32_t u = v.u;
  u = u + 0x7fffu + ((u >> 16) & 1u);
  return (unsigned short)(u >> 16);
}
__device__ __forceinline__ unsigned int cvtpk(float lo, float hi) {
  unsigned int r;
  asm("v_cvt_pk_bf16_f32 %0, %1, %2" : "=v"(r) : "v"(lo), "v"(hi));
  return r;
}
__device__ __forceinline__ void gload16(const void* g, void* lds) {
  __builtin_amdgcn_global_load_lds((const __attribute__((address_space(1))) void*)g,
                                   (__attribute__((address_space(3))) void*)lds, 16, 0, 0);
}

// ---------------- fp32 -> bf16 convert (x) ----------------
__global__ __launch_bounds__(256) void cvt_f32_bf16(const float* __restrict__ in,
                                                    unsigned short* __restrict__ out, int n) {
  int i = (blockIdx.x * 256 + threadIdx.x) * 4;
  if (i < n) {
    float4 v = *(const float4*)(in + i);
    ushort4 o;
    o.x = f2b(v.x); o.y = f2b(v.y); o.z = f2b(v.z); o.w = f2b(v.w);
    *(ushort4*)(out + i) = o;
  }
}

// ---------------- W [K][N] f32 -> Wt [N][K] bf16, rows < scaleRows scaled ----------------
__global__ __launch_bounds__(256) void transposeW(const float* __restrict__ W,
                                                  unsigned short* __restrict__ Wt,
                                                  int K, int N, float scale, int scaleRows) {
  __shared__ float tile[32][33];
  int x0 = blockIdx.x * 32, y0 = blockIdx.y * 32;
  int tx = threadIdx.x, ty = threadIdx.y;
  #pragma unroll
  for (int j = 0; j < 4; ++j)
    tile[ty + j * 8][tx] = W[(size_t)(y0 + ty + j * 8) * N + x0 + tx];
  __syncthreads();
  #pragma unroll
  for (int j = 0; j < 4; ++j) {
    int orow = x0 + ty + j * 8;
    float s = (orow < scaleRows) ? scale : 1.0f;
    Wt[(size_t)orow * K + y0 + tx] = f2b(tile[tx][ty + j * 8] * s);
  }
}

// ---------------- GEMM: C[M][N] = A[M][K] * Bt[N][K]^T + bias ----------------
// 128xBN tile, BK=64, 4 waves (2m x 2n). gload_lds w=16, both-sides XOR swizzle,
// XCD-swizzled 1D grid, double-buffered LDS (prefetch, ONE barrier/iter).
// If vtOut != nullptr and n0 >= 2048 (V-columns of qkv), the tile is written
// TRANSPOSED to vtOut[bh*64+dh][s] instead of outp (fuses transposeV).
template<bool OUTF32, int BN>
__global__ __launch_bounds__(256, 3) void gemm_bt(const unsigned short* __restrict__ A,
                                                  const unsigned short* __restrict__ Bt,
                                                  const float* __restrict__ bias,
                                                  void* __restrict__ outp,
                                                  unsigned short* __restrict__ vtOut,
                                                  int M, int N, int K,
                                                  float bscale, int bscaleN, int mtiles) {
  constexpr int FN = BN / 32;            // per-wave n-frags (wave covers BN/2 cols)
  __shared__ unsigned short As[2][128 * 64];
  __shared__ unsigned short Bs[2][BN * 64];
  const int t = threadIdx.x;
  const int lane = t & 63;
  const int w = t >> 6;
  const int wm = w >> 1, wn = w & 1;

  const int cpx = gridDim.x >> 3;
  const int swz = (blockIdx.x & 7) * cpx + (blockIdx.x >> 3);
  const int m0 = (swz % mtiles) * 128;
  const int n0 = (swz / mtiles) * BN;

  const f32x4 zero = {0.f, 0.f, 0.f, 0.f};
  f32x4 acc[4][FN];
  #pragma unroll
  for (int i = 0; i < 4; ++i)
    #pragma unroll
    for (int j = 0; j < FN; ++j) acc[i][j] = zero;

  const int cl = lane & 15, g = lane >> 4;
  const int srow = t >> 3;               // 0..31
  const int sch  = (t & 7) ^ (srow & 7); // pre-swizzled source chunk

  auto stage = [&](int k0, int buf) {
    #pragma unroll
    for (int r = 0; r < 4; ++r)
      gload16(A + (size_t)(m0 + r * 32 + srow) * K + k0 + sch * 8,
              (char*)As[buf] + r * 4096 + t * 16);
    #pragma unroll
    for (int r = 0; r < BN / 32; ++r)
      gload16(Bt + (size_t)(n0 + r * 32 + srow) * K + k0 + sch * 8,
              (char*)Bs[buf] + r * 4096 + t * 16);
  };

  stage(0, 0);
  __syncthreads();                       // buf0 ready (vmcnt drained)

  const int nk = K >> 6;
  for (int ki = 0; ki < nk; ++ki) {
    const int cur = ki & 1;
    if (ki + 1 < nk) stage((ki + 1) << 6, cur ^ 1);   // prefetch, don't wait
    char* AsB = (char*)As[cur];
    char* BsB = (char*)Bs[cur];
    #pragma unroll
    for (int kk = 0; kk < 2; ++kk) {
      short8 af[4], bfr[FN];
      #pragma unroll
      for (int f = 0; f < 4; ++f) {
        int arow = wm * 64 + f * 16 + cl;
        af[f]  = *(const short8*)(AsB + ((arow * 128 + kk * 64 + g * 16) ^ ((cl & 7) << 4)));
      }
      #pragma unroll
      for (int f = 0; f < FN; ++f) {
        int brow = wn * (BN / 2) + f * 16 + cl;
        bfr[f] = *(const short8*)(BsB + ((brow * 128 + kk * 64 + g * 16) ^ ((cl & 7) << 4)));
      }
      #pragma unroll
      for (int fm = 0; fm < 4; ++fm)
        #pragma unroll
        for (int fn = 0; fn < FN; ++fn)
          acc[fm][fn] = __builtin_amdgcn_mfma_f32_16x16x32_bf16(af[fm], bfr[fn], acc[fm][fn], 0, 0, 0);
    }
    __syncthreads();                     // drains prefetch (latency hidden) + rw sync
  }

  const bool vpath = (!OUTF32) && (vtOut != nullptr) && (n0 >= 2048);
  #pragma unroll
  for (int fn = 0; fn < FN; ++fn) {
    int col = n0 + wn * (BN / 2) + fn * 16 + cl;
    float bv = bias[col] * ((col < bscaleN) ? bscale : 1.0f);
    if (vpath) {
      // V^T write: vt[((b*16+h)*64+dh)][s], s = row & 2047
      int hcol = col - 2048;
      size_t vrow = (size_t)hcol * 2048;   // (h*64+dh)*2048; b added via row
      #pragma unroll
      for (int fm = 0; fm < 4; ++fm) {
        int rbase = m0 + wm * 64 + fm * 16 + g * 4;
        int b = rbase >> 11, s = rbase & 2047;
        ushort4 ov;
        ov.x = f2b(acc[fm][fn][0] + bv);
        ov.y = f2b(acc[fm][fn][1] + bv);
        ov.z = f2b(acc[fm][fn][2] + bv);
        ov.w = f2b(acc[fm][fn][3] + bv);
        *(ushort4*)(vtOut + (size_t)b * 1024 * 2048 + vrow + s) = ov;
      }
    } else {
      #pragma unroll
      for (int fm = 0; fm < 4; ++fm) {
        int rbase = m0 + wm * 64 + fm * 16 + g * 4;
        #pragma unroll
        for (int r = 0; r < 4; ++r) {
          float vout = acc[fm][fn][r] + bv;
          if (OUTF32) ((float*)outp)[(size_t)(rbase + r) * N + col] = vout;
          else ((unsigned short*)outp)[(size_t)(rbase + r) * N + col] = f2b(vout);
        }
      }
    }
  }
}

// ---------------- MFMA causal flash attention v5 ----------------
// One 64-row q-tile per block (4 waves, 16 rows/wave), kv-tile 64, dbuf K/V.
// Grid 1024 blocks, big-qt dispatched first (LPT balance), same-bh blocks land
// on the same XCD (bh determined by idx&7 -> its 512KB K/V fits XCD L2).
// Swapped QK^T / swapped PV (lane-local softmax stats), pre-scaled Q,
// l via ones-row PV MFMA, defer-max THR=8.
__global__ __launch_bounds__(256, 3) void attn_mfma3(const unsigned short* __restrict__ qkv,
                                                     const unsigned short* __restrict__ Vt,
                                                     unsigned short* __restrict__ ctx) {
  const int idx = blockIdx.x;
  const int bh = ((idx & 7) << 2) | ((idx >> 3) & 3);
  const int qt = 31 - (idx >> 5);
  const int b = bh >> 4, h = bh & 15;
  const int t = threadIdx.x;
  const int l = t & 63;
  const int w = t >> 6;
  const int cl = l & 15;
  const int g  = l >> 4;

  __shared__ unsigned short Ks[2][64 * 64];
  __shared__ unsigned short Vs[2][64 * 64];
  __shared__ unsigned short Ps[4][16 * 64];
  __shared__ unsigned short Ones[16 * 64];

  char* Pbuf = (char*)(&Ps[w][0]);
  char* OnB = (char*)Ones;

  const size_t kbase  = (size_t)(b * 2048) * 3072 + 1024 + h * 64;
  const size_t vtbase = (size_t)(bh * 64) * 2048;

  auto stage = [&](int jt, int buf) {
    #pragma unroll
    for (int i = 0; i < 2; ++i) {
      int row = i * 32 + w * 8 + (l >> 3);
      int ch  = (l & 7) ^ (l >> 3);        // (l&7) ^ (row&7)
      gload16(qkv + kbase + (size_t)(jt * 64 + row) * 3072 + ch * 8,
              (char*)Ks[buf] + i * 4096 + w * 1024);
      gload16(Vt + vtbase + (size_t)row * 2048 + jt * 64 + ch * 8,
              (char*)Vs[buf] + i * 4096 + w * 1024);
    }
  };

  // ones-tile: row 0 = 1.0bf16, rows 1..15 = 0 (same swizzle family as Vs)
  {
    int row = t >> 4;
    int c4  = (t & 15) * 4;
    unsigned short vv = (row == 0) ? (unsigned short)0x3F80 : (unsigned short)0;
    ushort4 ov = {vv, vv, vv, vv};
    *(ushort4*)(OnB + ((row * 128 + c4 * 2) ^ ((row & 7) << 4))) = ov;
  }

  stage(0, 0);                // prologue prefetch
  __syncthreads();            // buf0 + Ones ready

  short8 a5[2];
  #pragma unroll
  for (int kk = 0; kk < 2; ++kk)
    a5[kk] = *(const short8*)(OnB + ((cl * 128 + kk * 64 + g * 16) ^ ((cl & 7) << 4)));

  // Q fragment (pre-scaled by QSCALE via W_q/b_q), B-layout: col=q=cl, k=d
  short8 bq[2];
  {
    const unsigned short* qp = qkv + (size_t)(b * 2048 + qt * 64 + w * 16 + cl) * 3072 + h * 64 + g * 8;
    bq[0] = *(const short8*)(qp);
    bq[1] = *(const short8*)(qp + 32);
  }

  f32x4 o[4], o5;
  #pragma unroll
  for (int c = 0; c < 4; ++c) o[c] = (f32x4){0.f, 0.f, 0.f, 0.f};
  o5 = (f32x4){0.f, 0.f, 0.f, 0.f};
  float m = -1e30f;

  for (int jt = 0; jt <= qt; ++jt) {
    const int cur = jt & 1;
    if (jt < qt) stage(jt + 1, cur ^ 1);   // prefetch next tile, don't wait
    char* KsB = (char*)Ks[cur];
    char* VsB = (char*)Vs[cur];

    // A-frag K: row=kv=tt*16+cl, k=d
    short8 ak[4][2];
    #pragma unroll
    for (int tt = 0; tt < 4; ++tt)
      #pragma unroll
      for (int kk = 0; kk < 2; ++kk)
        ak[tt][kk] = *(const short8*)(KsB + (((tt * 16 + cl) * 128 + kk * 64 + g * 16) ^ ((cl & 7) << 4)));
    // A-frag V^T: row=d=c*16+cl, k=kv
    short8 av[4][2];
    #pragma unroll
    for (int c = 0; c < 4; ++c)
      #pragma unroll
      for (int kk = 0; kk < 2; ++kk)
        av[c][kk] = *(const short8*)(VsB + (((c * 16 + cl) * 128 + kk * 64 + g * 16) ^ ((cl & 7) << 4)));

    // ---- QK^T ----
    f32x4 st[4];
    #pragma unroll
    for (int tt = 0; tt < 4; ++tt) st[tt] = (f32x4){0.f, 0.f, 0.f, 0.f};
    __builtin_amdgcn_s_setprio(1);
    #pragma unroll
    for (int kk = 0; kk < 2; ++kk)
      #pragma unroll
      for (int tt = 0; tt < 4; ++tt)
        st[tt] = __builtin_amdgcn_mfma_f32_16x16x32_bf16(ak[tt][kk], bq[kk], st[tt], 0, 0, 0);
    __builtin_amdgcn_s_setprio(0);

    // ---- softmax (z in exp2 domain; kv_loc = tt*16+4g+r, q row = cl) ----
    float z[4][4];
    #pragma unroll
    for (int tt = 0; tt < 4; ++tt)
      #pragma unroll
      for (int r = 0; r < 4; ++r) z[tt][r] = st[tt][r];
    if (jt == qt) {
      int q_loc = w * 16 + cl;
      #pragma unroll
      for (int tt = 0; tt < 4; ++tt)
        #pragma unroll
        for (int r = 0; r < 4; ++r)
          if (tt * 16 + 4 * g + r > q_loc) z[tt][r] = -1e30f;
    }
    // pairwise max tree (shorter dep chain than serial)
    float m0a = fmaxf(fmaxf(z[0][0], z[0][1]), fmaxf(z[0][2], z[0][3]));
    float m1a = fmaxf(fmaxf(z[1][0], z[1][1]), fmaxf(z[1][2], z[1][3]));
    float m2a = fmaxf(fmaxf(z[2][0], z[2][1]), fmaxf(z[2][2], z[2][3]));
    float m3a = fmaxf(fmaxf(z[3][0], z[3][1]), fmaxf(z[3][2], z[3][3]));
    float cm = fmaxf(fmaxf(m0a, m1a), fmaxf(m2a, m3a));
    cm = fmaxf(cm, __shfl_xor(cm, 16));
    cm = fmaxf(cm, __shfl_xor(cm, 32));

    if (!__all(cm <= m + 8.f)) {           // defer-max THR=8
      float mn = fmaxf(m, cm);
      float alpha = exp2f(m - mn);
      m = mn;
      #pragma unroll
      for (int c = 0; c < 4; ++c)
        #pragma unroll
        for (int r = 0; r < 4; ++r) o[c][r] *= alpha;
      o5[0] *= alpha;
    }

    #pragma unroll
    for (int tt = 0; tt < 4; ++tt) {
      float p0 = exp2f(z[tt][0] - m), p1 = exp2f(z[tt][1] - m);
      float p2 = exp2f(z[tt][2] - m), p3 = exp2f(z[tt][3] - m);
      uint2 val;
      val.x = cvtpk(p0, p1);
      val.y = cvtpk(p2, p3);
      *(uint2*)(Pbuf + ((cl * 128 + tt * 32 + g * 8) ^ ((cl & 7) << 4))) = val;
    }
    short8 bp[2];
    #pragma unroll
    for (int kk = 0; kk < 2; ++kk)
      bp[kk] = *(const short8*)(Pbuf + ((cl * 128 + kk * 64 + g * 16) ^ ((cl & 7) << 4)));

    // ---- PV (+ ones-row for l) ----
    __builtin_amdgcn_s_setprio(1);
    #pragma unroll
    for (int kk = 0; kk < 2; ++kk) {
      #pragma unroll
      for (int c = 0; c < 4; ++c)
        o[c] = __builtin_amdgcn_mfma_f32_16x16x32_bf16(av[c][kk], bp[kk], o[c], 0, 0, 0);
      o5 = __builtin_amdgcn_mfma_f32_16x16x32_bf16(a5[kk], bp[kk], o5, 0, 0, 0);
    }
    __builtin_amdgcn_s_setprio(0);

    __syncthreads();   // drains prefetch (latency hidden) + rw sync
  }

  // epilogue: lane holds O^T[d=c*16+4g+r][q=cl]; l lives in o5[0] on g==0 lanes
  float lsum = __shfl(o5[0], cl);
  float inv = 1.f / lsum;
  unsigned short* crow = ctx + (size_t)(b * 2048 + qt * 64 + w * 16 + cl) * 1024 + h * 64 + g * 4;
  #pragma unroll
  for (int c = 0; c < 4; ++c) {
    uint2 val;
    val.x = cvtpk(o[c][0] * inv, o[c][1] * inv);
    val.y = cvtpk(o[c][2] * inv, o[c][3] * inv);
    *(uint2*)(crow + c * 16) = val;
  }
}

// ---------------- launch ----------------
extern "C" void kernel_launch(void* const* d_in, const int* in_sizes, int n_in,
                              void* d_out, int out_size, void* d_ws, size_t ws_size,
                              hipStream_t stream) {
  const float* x     = (const float*)d_in[0];   // [2,2048,1024]
  const float* Wqkv  = (const float*)d_in[1];   // [1024,3072]
  const float* bqkv  = (const float*)d_in[2];   // [3072]
  const float* Wproj = (const float*)d_in[3];   // [1024,1024]
  const float* bproj = (const float*)d_in[4];   // [1024]
  float* out = (float*)d_out;

  char* ws = (char*)d_ws;
  unsigned short* xb     = (unsigned short*)(ws);                 //  8 MB [4096][1024]
  unsigned short* wqkvT  = (unsigned short*)(ws + 8388608);       //  6 MB [3072][1024]
  unsigned short* wprojT = (unsigned short*)(ws + 14680064);      //  2 MB [1024][1024]
  unsigned short* qkv    = (unsigned short*)(ws + 16777216);      // 24 MB [4096][3072] (V-part unused)
  unsigned short* ctx    = (unsigned short*)(ws + 41943040);      //  8 MB [4096][1024]
  unsigned short* vt     = (unsigned short*)(ws + 50331648);      //  8 MB [32][64][2048]

  cvt_f32_bf16<<<4096, 256, 0, stream>>>(x, xb, 4096 * 1024);

  dim3 tb(32, 8);
  transposeW<<<dim3(3072 / 32, 1024 / 32), tb, 0, stream>>>(Wqkv, wqkvT, 1024, 3072, QSCALE, 1024);
  transposeW<<<dim3(1024 / 32, 1024 / 32), tb, 0, stream>>>(Wproj, wprojT, 1024, 1024, 1.0f, 0);

  // qkv GEMM: grid 32x24 = 768 (1D, %8==0); V-columns written transposed into vt
  gemm_bt<false, 128><<<768, 256, 0, stream>>>(xb, wqkvT, bqkv, qkv, vt,
                                               4096, 3072, 1024, QSCALE, 1024, 32);

  attn_mfma3<<<1024, 256, 0, stream>>>(qkv, vt, ctx);

  // proj GEMM: 128x64 tiles, grid 32x16 = 512
  gemm_bt<true, 64><<<512, 256, 0, stream>>>(ctx, wprojT, bproj, out, nullptr,
                                             4096, 1024, 1024, 1.0f, 0, 32);
}

// Round 8
// 181.503 us; speedup vs baseline: 5.9840x; 1.0566x over previous
//
#include <hip/hip_runtime.h>
#include <stdint.h>

typedef __attribute__((ext_vector_type(8))) short short8;
typedef __attribute__((ext_vector_type(4))) float f32x4;

#define QSCALE 0.18033688011112043f   // (1/sqrt(64)) * log2(e), folded into W_q/b_q

__device__ __forceinline__ unsigned short f2b(float f) {
  union { float f; uint32_t u; } v; v.f = f;
  uint32_t u = v.u;
  u = u + 0x7fffu + ((u >> 16) & 1u);
  return (unsigned short)(u >> 16);
}
__device__ __forceinline__ unsigned int cvtpk(float lo, float hi) {
  unsigned int r;
  asm("v_cvt_pk_bf16_f32 %0, %1, %2" : "=v"(r) : "v"(lo), "v"(hi));
  return r;
}
__device__ __forceinline__ void gload16(const void* g, void* lds) {
  __builtin_amdgcn_global_load_lds((const __attribute__((address_space(1))) void*)g,
                                   (__attribute__((address_space(3))) void*)lds, 16, 0, 0);
}

// ---------------- fp32 -> bf16 convert (x) ----------------
__global__ __launch_bounds__(256) void cvt_f32_bf16(const float* __restrict__ in,
                                                    unsigned short* __restrict__ out, int n) {
  int i = (blockIdx.x * 256 + threadIdx.x) * 4;
  if (i < n) {
    float4 v = *(const float4*)(in + i);
    ushort4 o;
    o.x = f2b(v.x); o.y = f2b(v.y); o.z = f2b(v.z); o.w = f2b(v.w);
    *(ushort4*)(out + i) = o;
  }
}

// ---------------- W [K][N] f32 -> Wt [N][K] bf16, rows < scaleRows scaled ----------------
__global__ __launch_bounds__(256) void transposeW(const float* __restrict__ W,
                                                  unsigned short* __restrict__ Wt,
                                                  int K, int N, float scale, int scaleRows) {
  __shared__ float tile[32][33];
  int x0 = blockIdx.x * 32, y0 = blockIdx.y * 32;
  int tx = threadIdx.x, ty = threadIdx.y;
  #pragma unroll
  for (int j = 0; j < 4; ++j)
    tile[ty + j * 8][tx] = W[(size_t)(y0 + ty + j * 8) * N + x0 + tx];
  __syncthreads();
  #pragma unroll
  for (int j = 0; j < 4; ++j) {
    int orow = x0 + ty + j * 8;
    float s = (orow < scaleRows) ? scale : 1.0f;
    Wt[(size_t)orow * K + y0 + tx] = f2b(tile[tx][ty + j * 8] * s);
  }
}

// ---------------- GEMM: C[M][N] = A[M][K] * Bt[N][K]^T + bias ----------------
// 128xBN tile, BK=32, 4 waves (2m x 2n), double-buffered (ONE barrier/iter).
// LDS tiles k-PACKED: logical rows r and r+ROWS/2 share a 128B phys row as
// chunk halves -> same proven zero-conflict ^((row&7)<<4) swizzle as BK=64.
// LDS: As 16KB + Bs 16/8KB -> 32/24KB -> 3 blocks/CU resident.
// If vtOut != nullptr and n0 >= 2048 (V-columns of qkv), tile is written
// TRANSPOSED to vtOut[bh*64+dh][s] (fuses transposeV).
template<bool OUTF32, int BN>
__global__ __launch_bounds__(256, 3) void gemm_bt(const unsigned short* __restrict__ A,
                                                  const unsigned short* __restrict__ Bt,
                                                  const float* __restrict__ bias,
                                                  void* __restrict__ outp,
                                                  unsigned short* __restrict__ vtOut,
                                                  int M, int N, int K,
                                                  float bscale, int bscaleN, int mtiles) {
  constexpr int FN = BN / 32;            // per-wave n-frags
  constexpr int BH = BN / 2;             // B phys rows
  __shared__ unsigned short As[2][64 * 64];        // 8KB/buf (128 log rows packed)
  __shared__ unsigned short Bs[2][BH * 64];        // BN=128: 8KB; BN=64: 4KB
  const int t = threadIdx.x;
  const int lane = t & 63;
  const int w = t >> 6;
  const int wm = w >> 1, wn = w & 1;

  const int cpx = gridDim.x >> 3;
  const int swz = (blockIdx.x & 7) * cpx + (blockIdx.x >> 3);
  const int m0 = (swz % mtiles) * 128;
  const int n0 = (swz / mtiles) * BN;

  const f32x4 zero = {0.f, 0.f, 0.f, 0.f};
  f32x4 acc[4][FN];
  #pragma unroll
  for (int i = 0; i < 4; ++i)
    #pragma unroll
    for (int j = 0; j < FN; ++j) acc[i][j] = zero;

  const int cl = lane & 15, g = lane >> 4;
  const int prow = t >> 3;               // phys row within 4KB round: 0..31
  const int pc   = (t & 7) ^ (prow & 7); // logical chunk stored at this slot

  auto stage = [&](int k0, int buf) {
    #pragma unroll
    for (int r = 0; r < 2; ++r) {
      int lrow = r * 32 + prow + 64 * (pc >> 2);     // logical A row 0..127
      gload16(A + (size_t)(m0 + lrow) * K + k0 + (pc & 3) * 8,
              (char*)As[buf] + r * 4096 + t * 16);
    }
    #pragma unroll
    for (int r = 0; r < BN / 64; ++r) {
      int lrow = r * 32 + prow + BH * (pc >> 2);     // logical B row 0..BN-1
      gload16(Bt + (size_t)(n0 + lrow) * K + k0 + (pc & 3) * 8,
              (char*)Bs[buf] + r * 4096 + t * 16);
    }
  };

  stage(0, 0);
  __syncthreads();                       // buf0 ready (vmcnt drained)

  const int nk = K >> 5;
  for (int ki = 0; ki < nk; ++ki) {
    const int cur = ki & 1;
    if (ki + 1 < nk) stage((ki + 1) << 5, cur ^ 1);   // prefetch, don't wait
    char* AsB = (char*)As[cur];
    char* BsB = (char*)Bs[cur];
    short8 af[4], bfr[FN];
    #pragma unroll
    for (int f = 0; f < 4; ++f) {
      int pr = f * 16 + cl;              // phys row (wm selects chunk-half)
      af[f] = *(const short8*)(AsB + pr * 128 + ((((wm << 2) + g) ^ (pr & 7)) << 4));
    }
    #pragma unroll
    for (int f = 0; f < FN; ++f) {
      int lr = wn * BH + f * 16 + cl;
      int pr = lr & (BH - 1);
      bfr[f] = *(const short8*)(BsB + pr * 128 + ((((wn << 2) + g) ^ (pr & 7)) << 4));
    }
    #pragma unroll
    for (int fm = 0; fm < 4; ++fm)
      #pragma unroll
      for (int fn = 0; fn < FN; ++fn)
        acc[fm][fn] = __builtin_amdgcn_mfma_f32_16x16x32_bf16(af[fm], bfr[fn], acc[fm][fn], 0, 0, 0);
    __syncthreads();                     // drains prefetch (latency hidden) + rw sync
  }

  const bool vpath = (!OUTF32) && (vtOut != nullptr) && (n0 >= 2048);
  #pragma unroll
  for (int fn = 0; fn < FN; ++fn) {
    int col = n0 + wn * BH + fn * 16 + cl;
    float bv = bias[col] * ((col < bscaleN) ? bscale : 1.0f);
    if (vpath) {
      int hcol = col - 2048;
      size_t vrow = (size_t)hcol * 2048;
      #pragma unroll
      for (int fm = 0; fm < 4; ++fm) {
        int rbase = m0 + wm * 64 + fm * 16 + g * 4;
        int b = rbase >> 11, s = rbase & 2047;
        ushort4 ov;
        ov.x = f2b(acc[fm][fn][0] + bv);
        ov.y = f2b(acc[fm][fn][1] + bv);
        ov.z = f2b(acc[fm][fn][2] + bv);
        ov.w = f2b(acc[fm][fn][3] + bv);
        *(ushort4*)(vtOut + (size_t)b * 1024 * 2048 + vrow + s) = ov;
      }
    } else {
      #pragma unroll
      for (int fm = 0; fm < 4; ++fm) {
        int rbase = m0 + wm * 64 + fm * 16 + g * 4;
        #pragma unroll
        for (int r = 0; r < 4; ++r) {
          float vout = acc[fm][fn][r] + bv;
          if (OUTF32) ((float*)outp)[(size_t)(rbase + r) * N + col] = vout;
          else ((unsigned short*)outp)[(size_t)(rbase + r) * N + col] = f2b(vout);
        }
      }
    }
  }
}

// ---------------- MFMA causal flash attention v5 (unchanged from r7) ----------------
__global__ __launch_bounds__(256, 3) void attn_mfma3(const unsigned short* __restrict__ qkv,
                                                     const unsigned short* __restrict__ Vt,
                                                     unsigned short* __restrict__ ctx) {
  const int idx = blockIdx.x;
  const int bh = ((idx & 7) << 2) | ((idx >> 3) & 3);
  const int qt = 31 - (idx >> 5);
  const int b = bh >> 4, h = bh & 15;
  const int t = threadIdx.x;
  const int l = t & 63;
  const int w = t >> 6;
  const int cl = l & 15;
  const int g  = l >> 4;

  __shared__ unsigned short Ks[2][64 * 64];
  __shared__ unsigned short Vs[2][64 * 64];
  __shared__ unsigned short Ps[4][16 * 64];
  __shared__ unsigned short Ones[16 * 64];

  char* Pbuf = (char*)(&Ps[w][0]);
  char* OnB = (char*)Ones;

  const size_t kbase  = (size_t)(b * 2048) * 3072 + 1024 + h * 64;
  const size_t vtbase = (size_t)(bh * 64) * 2048;

  auto stage = [&](int jt, int buf) {
    #pragma unroll
    for (int i = 0; i < 2; ++i) {
      int row = i * 32 + w * 8 + (l >> 3);
      int ch  = (l & 7) ^ (l >> 3);
      gload16(qkv + kbase + (size_t)(jt * 64 + row) * 3072 + ch * 8,
              (char*)Ks[buf] + i * 4096 + w * 1024);
      gload16(Vt + vtbase + (size_t)row * 2048 + jt * 64 + ch * 8,
              (char*)Vs[buf] + i * 4096 + w * 1024);
    }
  };

  {
    int row = t >> 4;
    int c4  = (t & 15) * 4;
    unsigned short vv = (row == 0) ? (unsigned short)0x3F80 : (unsigned short)0;
    ushort4 ov = {vv, vv, vv, vv};
    *(ushort4*)(OnB + ((row * 128 + c4 * 2) ^ ((row & 7) << 4))) = ov;
  }

  stage(0, 0);
  __syncthreads();

  short8 a5[2];
  #pragma unroll
  for (int kk = 0; kk < 2; ++kk)
    a5[kk] = *(const short8*)(OnB + ((cl * 128 + kk * 64 + g * 16) ^ ((cl & 7) << 4)));

  short8 bq[2];
  {
    const unsigned short* qp = qkv + (size_t)(b * 2048 + qt * 64 + w * 16 + cl) * 3072 + h * 64 + g * 8;
    bq[0] = *(const short8*)(qp);
    bq[1] = *(const short8*)(qp + 32);
  }

  f32x4 o[4], o5;
  #pragma unroll
  for (int c = 0; c < 4; ++c) o[c] = (f32x4){0.f, 0.f, 0.f, 0.f};
  o5 = (f32x4){0.f, 0.f, 0.f, 0.f};
  float m = -1e30f;

  for (int jt = 0; jt <= qt; ++jt) {
    const int cur = jt & 1;
    if (jt < qt) stage(jt + 1, cur ^ 1);
    char* KsB = (char*)Ks[cur];
    char* VsB = (char*)Vs[cur];

    short8 ak[4][2];
    #pragma unroll
    for (int tt = 0; tt < 4; ++tt)
      #pragma unroll
      for (int kk = 0; kk < 2; ++kk)
        ak[tt][kk] = *(const short8*)(KsB + (((tt * 16 + cl) * 128 + kk * 64 + g * 16) ^ ((cl & 7) << 4)));
    short8 av[4][2];
    #pragma unroll
    for (int c = 0; c < 4; ++c)
      #pragma unroll
      for (int kk = 0; kk < 2; ++kk)
        av[c][kk] = *(const short8*)(VsB + (((c * 16 + cl) * 128 + kk * 64 + g * 16) ^ ((cl & 7) << 4)));

    f32x4 st[4];
    #pragma unroll
    for (int tt = 0; tt < 4; ++tt) st[tt] = (f32x4){0.f, 0.f, 0.f, 0.f};
    __builtin_amdgcn_s_setprio(1);
    #pragma unroll
    for (int kk = 0; kk < 2; ++kk)
      #pragma unroll
      for (int tt = 0; tt < 4; ++tt)
        st[tt] = __builtin_amdgcn_mfma_f32_16x16x32_bf16(ak[tt][kk], bq[kk], st[tt], 0, 0, 0);
    __builtin_amdgcn_s_setprio(0);

    float z[4][4];
    #pragma unroll
    for (int tt = 0; tt < 4; ++tt)
      #pragma unroll
      for (int r = 0; r < 4; ++r) z[tt][r] = st[tt][r];
    if (jt == qt) {
      int q_loc = w * 16 + cl;
      #pragma unroll
      for (int tt = 0; tt < 4; ++tt)
        #pragma unroll
        for (int r = 0; r < 4; ++r)
          if (tt * 16 + 4 * g + r > q_loc) z[tt][r] = -1e30f;
    }
    float m0a = fmaxf(fmaxf(z[0][0], z[0][1]), fmaxf(z[0][2], z[0][3]));
    float m1a = fmaxf(fmaxf(z[1][0], z[1][1]), fmaxf(z[1][2], z[1][3]));
    float m2a = fmaxf(fmaxf(z[2][0], z[2][1]), fmaxf(z[2][2], z[2][3]));
    float m3a = fmaxf(fmaxf(z[3][0], z[3][1]), fmaxf(z[3][2], z[3][3]));
    float cm = fmaxf(fmaxf(m0a, m1a), fmaxf(m2a, m3a));
    cm = fmaxf(cm, __shfl_xor(cm, 16));
    cm = fmaxf(cm, __shfl_xor(cm, 32));

    if (!__all(cm <= m + 8.f)) {
      float mn = fmaxf(m, cm);
      float alpha = exp2f(m - mn);
      m = mn;
      #pragma unroll
      for (int c = 0; c < 4; ++c)
        #pragma unroll
        for (int r = 0; r < 4; ++r) o[c][r] *= alpha;
      o5[0] *= alpha;
    }

    #pragma unroll
    for (int tt = 0; tt < 4; ++tt) {
      float p0 = exp2f(z[tt][0] - m), p1 = exp2f(z[tt][1] - m);
      float p2 = exp2f(z[tt][2] - m), p3 = exp2f(z[tt][3] - m);
      uint2 val;
      val.x = cvtpk(p0, p1);
      val.y = cvtpk(p2, p3);
      *(uint2*)(Pbuf + ((cl * 128 + tt * 32 + g * 8) ^ ((cl & 7) << 4))) = val;
    }
    short8 bp[2];
    #pragma unroll
    for (int kk = 0; kk < 2; ++kk)
      bp[kk] = *(const short8*)(Pbuf + ((cl * 128 + kk * 64 + g * 16) ^ ((cl & 7) << 4)));

    __builtin_amdgcn_s_setprio(1);
    #pragma unroll
    for (int kk = 0; kk < 2; ++kk) {
      #pragma unroll
      for (int c = 0; c < 4; ++c)
        o[c] = __builtin_amdgcn_mfma_f32_16x16x32_bf16(av[c][kk], bp[kk], o[c], 0, 0, 0);
      o5 = __builtin_amdgcn_mfma_f32_16x16x32_bf16(a5[kk], bp[kk], o5, 0, 0, 0);
    }
    __builtin_amdgcn_s_setprio(0);

    __syncthreads();
  }

  float lsum = __shfl(o5[0], cl);
  float inv = 1.f / lsum;
  unsigned short* crow = ctx + (size_t)(b * 2048 + qt * 64 + w * 16 + cl) * 1024 + h * 64 + g * 4;
  #pragma unroll
  for (int c = 0; c < 4; ++c) {
    uint2 val;
    val.x = cvtpk(o[c][0] * inv, o[c][1] * inv);
    val.y = cvtpk(o[c][2] * inv, o[c][3] * inv);
    *(uint2*)(crow + c * 16) = val;
  }
}

// ---------------- launch ----------------
extern "C" void kernel_launch(void* const* d_in, const int* in_sizes, int n_in,
                              void* d_out, int out_size, void* d_ws, size_t ws_size,
                              hipStream_t stream) {
  const float* x     = (const float*)d_in[0];   // [2,2048,1024]
  const float* Wqkv  = (const float*)d_in[1];   // [1024,3072]
  const float* bqkv  = (const float*)d_in[2];   // [3072]
  const float* Wproj = (const float*)d_in[3];   // [1024,1024]
  const float* bproj = (const float*)d_in[4];   // [1024]
  float* out = (float*)d_out;

  char* ws = (char*)d_ws;
  unsigned short* xb     = (unsigned short*)(ws);                 //  8 MB [4096][1024]
  unsigned short* wqkvT  = (unsigned short*)(ws + 8388608);       //  6 MB [3072][1024]
  unsigned short* wprojT = (unsigned short*)(ws + 14680064);      //  2 MB [1024][1024]
  unsigned short* qkv    = (unsigned short*)(ws + 16777216);      // 24 MB [4096][3072] (V-part unused)
  unsigned short* ctx    = (unsigned short*)(ws + 41943040);      //  8 MB [4096][1024]
  unsigned short* vt     = (unsigned short*)(ws + 50331648);      //  8 MB [32][64][2048]

  cvt_f32_bf16<<<4096, 256, 0, stream>>>(x, xb, 4096 * 1024);

  dim3 tb(32, 8);
  transposeW<<<dim3(3072 / 32, 1024 / 32), tb, 0, stream>>>(Wqkv, wqkvT, 1024, 3072, QSCALE, 1024);
  transposeW<<<dim3(1024 / 32, 1024 / 32), tb, 0, stream>>>(Wproj, wprojT, 1024, 1024, 1.0f, 0);

  // qkv GEMM: grid 32x24 = 768 (1D, %8==0); V-columns written transposed into vt
  gemm_bt<false, 128><<<768, 256, 0, stream>>>(xb, wqkvT, bqkv, qkv, vt,
                                               4096, 3072, 1024, QSCALE, 1024, 32);

  attn_mfma3<<<1024, 256, 0, stream>>>(qkv, vt, ctx);

  // proj GEMM: 128x64 tiles, grid 32x16 = 512
  gemm_bt<true, 64><<<512, 256, 0, stream>>>(ctx, wprojT, bproj, out, nullptr,
                                             4096, 1024, 1024, 1.0f, 0, 32);
}